// Round 7
// baseline (334.666 us; speedup 1.0000x reference)
//
#include <hip/hip_runtime.h>

// ---------------------------------------------------------------------------
// BiMamba2 (D_MODEL=1024, D_INNER=2048, NHEADS=32, HEADDIM=64, D_STATE=128,
// D_CONV=4, B=4, L=1024).  Pipeline:
//   ln1 -> (bf16) -> GEMM1 (in-proj, bf16 out, BK=64) -> conv (16t-tiled)
//   -> dtprep -> chunked MFMA scan -> gate+RMS+combine -> GEMM2 -> ln2
//
// R14: p-split scan.  Evidence R8-R13: k_scan is bound by an exposed per-
// chunk latency chain; same-block waves can't hide it (R11) because they
// share the barrier.  The H-recurrence is parallel across p (HEADDIM), so
// each (db,h) task is split into TWO independent 128-thread blocks (half =
// p-range 0-31 / 32-63), each running the verbatim R7 per-chunk pipeline
// for its half: staging + G duplicated (wave0: tiles (0,0),(1,1); wave1:
// (1,0)), y/H formulas unchanged with p-offset half*32 + w*16.  LDS 48KB
// -> 3 blocks/CU capacity, grid 512 -> ~2 independent blocks/CU whose
// latency stalls interleave.  Halves of one (db,h) land on the same XCD
// (bid = half*256 + task) so duplicated B/C reads are L2-hits.
// Per-half arithmetic is order-identical to R7 -> absmax must match.
// ---------------------------------------------------------------------------

#define BSZ 4
#define SEQ 1024
#define DMODEL 1024
#define DINNER 2048
#define NHEADS 32
#define HEADDIM 64
#define DSTATE 128
#define CONVDIM 2304            // DINNER + 2*DSTATE
#define DPROJ 4384              // 2*DINNER + 2*DSTATE + NHEADS
#define DPROJ_PAD 4480          // padded to multiple of 128
#define NTOK (BSZ*SEQ)          // 4096
#define EPSF 1e-5f
#define CH 32                   // scan chunk length
#define NCHK (SEQ/CH)           // 32 chunks

typedef float f32x4 __attribute__((ext_vector_type(4)));
typedef __bf16 bf16x8 __attribute__((ext_vector_type(8)));
typedef __bf16 bf16x4 __attribute__((ext_vector_type(4)));

__device__ __forceinline__ unsigned short f2bf(float f) {
  unsigned int x = __float_as_uint(f);
  unsigned int r = (x + 0x7fffu + ((x >> 16) & 1u)) >> 16;
  return (unsigned short)r;
}
__device__ __forceinline__ float bf2f(unsigned short u) {
  return __uint_as_float(((unsigned int)u) << 16);
}

__device__ __forceinline__ void async_load16(const void* g, void* l) {
  __builtin_amdgcn_global_load_lds(
      (const __attribute__((address_space(1))) void*)g,
      (__attribute__((address_space(3))) void*)l, 16, 0, 0);
}

// ---------------------------------------------------------------------------
// Prep: weight conversion (merged) + lengths
// ---------------------------------------------------------------------------
#define W1N (DPROJ_PAD * DMODEL)
#define W2N (DMODEL * DINNER)
__global__ void k_convert(const float* __restrict__ w1, const float* __restrict__ w2,
                          unsigned short* __restrict__ o1, unsigned short* __restrict__ o2) {
  int idx = blockIdx.x * 256 + threadIdx.x;
  if (idx < W1N) {
    int row = idx >> 10, col = idx & 1023;
    float v = (row < DPROJ) ? w1[(size_t)row * DMODEL + col] : 0.f;
    o1[idx] = f2bf(v);
  } else {
    int k = idx - W1N;
    o2[k] = f2bf(w2[k]);
  }
}
__global__ void k_lengths(const unsigned char* __restrict__ mask, int* __restrict__ lengths) {
  int b = blockIdx.x, tid = threadIdx.x;
  int cnt = 0;
  for (int k = 0; k < 4; ++k)
    cnt += (mask[(size_t)b * SEQ + tid + k * 256] == 0) ? 1 : 0;
  for (int o = 32; o > 0; o >>= 1) cnt += __shfl_down(cnt, o);
  __shared__ int red[4];
  if ((tid & 63) == 0) red[tid >> 6] = cnt;
  __syncthreads();
  if (tid == 0) lengths[b] = red[0] + red[1] + red[2] + red[3];
}

// ---------------------------------------------------------------------------
// LayerNorm (1024 wide, fp32 in) -> bf16 out
// ---------------------------------------------------------------------------
__global__ __launch_bounds__(256) void k_ln_bf16(const float* __restrict__ in,
                                                 unsigned short* __restrict__ out) {
  int row = blockIdx.x, tid = threadIdx.x;
  float4 v = ((const float4*)(in + (size_t)row * DMODEL))[tid];
  float s = v.x + v.y + v.z + v.w;
  float ss = v.x * v.x + v.y * v.y + v.z * v.z + v.w * v.w;
  for (int o = 32; o > 0; o >>= 1) { s += __shfl_down(s, o); ss += __shfl_down(ss, o); }
  __shared__ float red[8];
  if ((tid & 63) == 0) { red[tid >> 6] = s; red[4 + (tid >> 6)] = ss; }
  __syncthreads();
  s = red[0] + red[1] + red[2] + red[3];
  ss = red[4] + red[5] + red[6] + red[7];
  float mu = s * (1.f / DMODEL);
  float var = ss * (1.f / DMODEL) - mu * mu;
  float rs = rsqrtf(var + EPSF);
  ushort4 o;
  o.x = f2bf((v.x - mu) * rs); o.y = f2bf((v.y - mu) * rs);
  o.z = f2bf((v.z - mu) * rs); o.w = f2bf((v.w - mu) * rs);
  ((ushort4*)(out + (size_t)row * DMODEL))[tid] = o;
}

// LayerNorm (1024 wide, bf16 in) -> fp32 out (final)
__global__ __launch_bounds__(256) void k_ln_out(const unsigned short* __restrict__ in,
                                                float* __restrict__ out) {
  int row = blockIdx.x, tid = threadIdx.x;
  ushort4 u = ((const ushort4*)(in + (size_t)row * DMODEL))[tid];
  float4 v;
  v.x = bf2f(u.x); v.y = bf2f(u.y); v.z = bf2f(u.z); v.w = bf2f(u.w);
  float s = v.x + v.y + v.z + v.w;
  float ss = v.x * v.x + v.y * v.y + v.z * v.z + v.w * v.w;
  for (int o = 32; o > 0; o >>= 1) { s += __shfl_down(s, o); ss += __shfl_down(ss, o); }
  __shared__ float red[8];
  if ((tid & 63) == 0) { red[tid >> 6] = s; red[4 + (tid >> 6)] = ss; }
  __syncthreads();
  s = red[0] + red[1] + red[2] + red[3];
  ss = red[4] + red[5] + red[6] + red[7];
  float mu = s * (1.f / DMODEL);
  float var = ss * (1.f / DMODEL) - mu * mu;
  float rs = rsqrtf(var + EPSF);
  float4 o;
  o.x = (v.x - mu) * rs; o.y = (v.y - mu) * rs;
  o.z = (v.z - mu) * rs; o.w = (v.w - mu) * rs;
  ((float4*)(out + (size_t)row * DMODEL))[tid] = o;
}

// ---------------------------------------------------------------------------
// bf16 MFMA GEMM (B^T form): C[M,N] = A[M,K] * B[N,K]^T, bf16 out.
// ---------------------------------------------------------------------------
__global__ __launch_bounds__(256) void k_gemm_bt_h(const unsigned short* __restrict__ A,
                                                   const unsigned short* __restrict__ B,
                                                   unsigned short* __restrict__ C,
                                                   int K, int lda, int ldb, int ldc) {
  __shared__ unsigned short Asm[2][128 * 32];
  __shared__ unsigned short Bsm[2][128 * 32];
  const int tid = threadIdx.x;
  const int lane = tid & 63;
  const int w = tid >> 6;
  const int wm = w >> 1, wn = w & 1;
  const long m0 = (long)blockIdx.x * 128;
  const long n0 = (long)blockIdx.y * 128;

  const int sr = lane >> 2;
  const int sc = (lane & 3) * 8;
  const unsigned short* gA0 = A + (m0 + (w * 2 + 0) * 16 + sr) * (long)lda + sc;
  const unsigned short* gA1 = A + (m0 + (w * 2 + 1) * 16 + sr) * (long)lda + sc;
  const unsigned short* gB0 = B + (n0 + (w * 2 + 0) * 16 + sr) * (long)ldb + sc;
  const unsigned short* gB1 = B + (n0 + (w * 2 + 1) * 16 + sr) * (long)ldb + sc;

  f32x4 acc[4][4] = {};
  const int q8 = (lane >> 4) * 8;
  const int r16 = lane & 15;

  for (int k0 = 0; k0 < K; k0 += 64) {
#pragma unroll
    for (int h = 0; h < 2; ++h) {
      const int ko = k0 + h * 32;
      async_load16(gA0 + ko, Asm[h] + (w * 2 + 0) * 512);
      async_load16(gA1 + ko, Asm[h] + (w * 2 + 1) * 512);
      async_load16(gB0 + ko, Bsm[h] + (w * 2 + 0) * 512);
      async_load16(gB1 + ko, Bsm[h] + (w * 2 + 1) * 512);
    }
    __syncthreads();
#pragma unroll
    for (int h = 0; h < 2; ++h) {
      bf16x8 af[4], bfr[4];
#pragma unroll
      for (int i = 0; i < 4; ++i)
        af[i] = *reinterpret_cast<const bf16x8*>(Asm[h] + (wm * 64 + i * 16 + r16) * 32 + q8);
#pragma unroll
      for (int j = 0; j < 4; ++j)
        bfr[j] = *reinterpret_cast<const bf16x8*>(Bsm[h] + (wn * 64 + j * 16 + r16) * 32 + q8);
#pragma unroll
      for (int i = 0; i < 4; ++i)
#pragma unroll
        for (int j = 0; j < 4; ++j)
          acc[i][j] = __builtin_amdgcn_mfma_f32_16x16x32_bf16(af[i], bfr[j], acc[i][j], 0, 0, 0);
    }
    __syncthreads();
  }
  const int q = lane >> 4, cn = lane & 15;
#pragma unroll
  for (int i = 0; i < 4; ++i)
#pragma unroll
    for (int j = 0; j < 4; ++j) {
      long crow = m0 + wm * 64 + i * 16 + q * 4;
      long ccol = n0 + wn * 64 + j * 16 + cn;
#pragma unroll
      for (int r = 0; r < 4; ++r)
        C[(crow + r) * (long)ldc + ccol] = f2bf(acc[i][j][r]);
    }
}

// ---------------------------------------------------------------------------
// Depthwise causal conv (width 4) + SiLU over xBC slice (bf16 in) -> bf16.
// ---------------------------------------------------------------------------
__global__ __launch_bounds__(256) void k_conv(
    const __bf16* __restrict__ zxb,
    const float* __restrict__ cw_f, const float* __restrict__ cb_f,
    const float* __restrict__ cw_r, const float* __restrict__ cb_r,
    const int* __restrict__ lengths,
    __bf16* __restrict__ xb) {
  const int bx = blockIdx.x;                // db*64 + tg
  const int tg = bx & 63;
  const int db = bx >> 6;
  const int b = db & 3;
  const int dir = db >> 2;
  const int tid = threadIdx.x;
  const int len = lengths[b];
  const int t0 = tg * 16;

  const float* cw = dir ? cw_r : cw_f;
  const float* cb = dir ? cb_r : cb_f;

  float w0[9], w1[9], w2[9], w3[9], bias[9];
  float r0[9], r1[9], r2[9], r3[9];
#pragma unroll
  for (int k = 0; k < 9; ++k) {
    int c = tid + k * 256;
    float4 w4 = *(const float4*)(cw + (size_t)c * 4);
    w0[k] = w4.x; w1[k] = w4.y; w2[k] = w4.z; w3[k] = w4.w;
    bias[k] = cb[c];
    r0[k] = 0.f; r1[k] = 0.f; r2[k] = 0.f;
  }
  auto rowptr = [&](int tt) -> const __bf16* {
    int s = dir ? ((tt < len) ? (len - 1 - tt) : tt) : tt;
    return zxb + ((size_t)b * SEQ + s) * DPROJ_PAD + DINNER;
  };
  if (t0 >= 3) {
    const __bf16* ra = rowptr(t0 - 3);
    const __bf16* rb = rowptr(t0 - 2);
    const __bf16* rc = rowptr(t0 - 1);
#pragma unroll
    for (int k = 0; k < 9; ++k) {
      int c = tid + k * 256;
      r0[k] = (float)ra[c]; r1[k] = (float)rb[c]; r2[k] = (float)rc[c];
    }
  }
  {
    const __bf16* rp = rowptr(t0);
#pragma unroll
    for (int k = 0; k < 9; ++k) r3[k] = (float)rp[tid + k * 256];
  }
  for (int j = 0; j < 16; ++j) {
    float r4[9];
    if (j < 15) {
      const __bf16* rp = rowptr(t0 + j + 1);
#pragma unroll
      for (int k = 0; k < 9; ++k) r4[k] = (float)rp[tid + k * 256];
    }
    __bf16* orow = xb + ((size_t)db * SEQ + t0 + j) * CONVDIM;
#pragma unroll
    for (int k = 0; k < 9; ++k) {
      float acc = bias[k];
      acc = fmaf(w0[k], r0[k], acc);
      acc = fmaf(w1[k], r1[k], acc);
      acc = fmaf(w2[k], r2[k], acc);
      acc = fmaf(w3[k], r3[k], acc);
      float sig = 1.f / (1.f + __expf(-acc));
      orow[tid + k * 256] = (__bf16)(acc * sig);
      r0[k] = r1[k]; r1[k] = r2[k]; r2[k] = r3[k]; r3[k] = r4[k];
    }
  }
}

// ---------------------------------------------------------------------------
// dt/decay table precompute.  One 32-lane group per (db,h,chunk): 8192
// groups.  Layout ddg[task][128]: dt / cd=A*cum / W / P.
// ---------------------------------------------------------------------------
__global__ __launch_bounds__(256) void k_dtprep(
    const __bf16* __restrict__ zxb,
    const float* __restrict__ dtb_f, const float* __restrict__ dtb_r,
    const float* __restrict__ al_f, const float* __restrict__ al_r,
    const int* __restrict__ lengths, float* __restrict__ ddg) {
  const int task = (blockIdx.x * 256 + threadIdx.x) >> 5;  // (db*32+h)*32+chunk
  const int l32 = threadIdx.x & 31;
  const int chunk = task & 31, hh = (task >> 5) & 31, db = task >> 10;
  const int b = db & 3, dir = db >> 2;
  const int len = lengths[b];
  const float dtbv = (dir ? dtb_r : dtb_f)[hh];
  const float Ah = -__expf((dir ? al_r : al_f)[hh]);
  const int s = chunk * 32 + l32;
  const int sf = dir ? ((s < len) ? (len - 1 - s) : s) : s;
  float raw = (float)zxb[(size_t)(b * SEQ + sf) * DPROJ_PAD + DINNER + CONVDIM + hh] + dtbv;
  float d = (raw > 20.f) ? raw : log1pf(__expf(raw));
  float cum = d;
#pragma unroll
  for (int o = 1; o < 32; o <<= 1) {
    float v = __shfl_up(cum, o, 32);
    if (l32 >= o) cum += v;
  }
  float cum31 = __shfl(cum, 31, 32);
  float* o = ddg + (size_t)task * 128;
  o[l32]      = d;
  o[32 + l32] = Ah * cum;
  o[64 + l32] = d * __expf(Ah * (cum31 - cum));
  o[96 + l32] = __expf(Ah * cum);
}

// ---------------------------------------------------------------------------
// Chunked MFMA selective scan, p-split (R14): grid 512 = 2 halves x 256
// tasks; 128 threads / 2 waves per block.  Per-chunk pipeline is R7
// verbatim; wave w owns p-columns half*32 + w*16 .. +15.
//   G: wave0 tiles (0,0),(1,1); wave1 tile (1,0).
//   Staging: each wave issues 4 tile-slots (idx = w*4+k).
//   BT repack: 128 threads x 4 gathers.
//   yO: [32 t][40] stride (32 p + 8 pad), b128 flush (4 lanes/row).
// LDS 48KB static -> 3 blocks/CU capacity; ~2 resident (grid 512).
// ---------------------------------------------------------------------------
__global__ __launch_bounds__(128) void k_scan(
    const __bf16* __restrict__ xb, const float* __restrict__ ddg,
    const float* __restrict__ D_f, const float* __restrict__ D_r,
    unsigned short* __restrict__ y) {
  __shared__ __bf16 Crawf[4096];      // C frag-linear, 8 tiles (tt,kk)
  __shared__ __bf16 Brawf[4096];      // B frag-linear (B-as-rows x k=n)
  __shared__ __bf16 Braw2[4096];      // B row-major [s][n] (for BT repack)
  __shared__ __bf16 BTf[4096];        // B^T frag-linear, 8 tiles (nt)
  __shared__ float  ddL[2][128];      // dt/cd/W/P tables (double)
  __shared__ __bf16 SL[1024];         // S frag-linear, 2 tiles (t-halves)
  __shared__ __bf16 HL[2][2048];      // per-wave H frag-linear, 4 tiles (kk)
  __shared__ __bf16 yO[2][32 * 40];   // y half-chunk [t][p], stride 40

  const int bxi = blockIdx.x;
  const int half = bxi >> 8;          // p-range: half*32
  const int task = bxi & 255;         // db*32 + h
  const int h = task & 31;
  const int db = task >> 5;
  const int dir = db >> 2;
  const int tid = threadIdx.x;        // 0..127
  const int lane = tid & 63;
  const int w = tid >> 6;             // 0..1
  const int l15 = lane & 15;
  const int q = lane >> 4;

  const float Dh = (dir ? D_r : D_f)[h];
  const __bf16* xbase = xb + (size_t)db * SEQ * CONVDIM;
  const float* ddbase = ddg + (size_t)task * NCHK * 128;
  unsigned short* ybase = y + (size_t)db * SEQ * DINNER + h * HEADDIM + half * 32;

  for (int i = lane; i < 2048; i += 64) HL[w][i] = (__bf16)0.f;
  for (int i = tid; i < 1024; i += 128) SL[i] = (__bf16)0.f;

  f32x4 accH[8] = {};

  auto issue = [&](int c, int nb) {
    const __bf16* xr = xbase + (size_t)c * CH * CONVDIM;
#pragma unroll
    for (int k = 0; k < 4; ++k) {
      const int idx = w * 4 + k;              // 0..7
      const int P = idx * 64 + lane;
      const int tt = P >> 8, kk = (P >> 6) & 3, qq = (P >> 4) & 3, ll = P & 15;
      const __bf16* gB = xr + (size_t)(tt * 16 + ll) * CONVDIM + DINNER + kk * 32 + qq * 8;
      async_load16(gB, &Brawf[idx * 512]);
      async_load16(gB + 128, &Crawf[idx * 512]);
      const int s = P >> 4, n8 = P & 15;
      const __bf16* g2 = xr + (size_t)s * CONVDIM + DINNER + n8 * 8;
      async_load16(g2, &Braw2[idx * 512]);
    }
    if (w == 1 && lane < 32)
      async_load16(ddbase + (size_t)c * 128 + lane * 4, &ddL[nb][0]);
  };

  auto load_xt = [&](int c) {
    bf16x8 v;
    const __bf16* gx = xbase + (size_t)(c * CH + q * 8) * CONVDIM + h * HEADDIM
                       + half * 32 + w * 16 + l15;
#pragma unroll
    for (int j = 0; j < 8; ++j) v[j] = gx[(size_t)j * CONVDIM];
    return v;
  };

  issue(0, 0);
  bf16x8 xt = load_xt(0);
  __syncthreads();

  for (int c = 0; c < NCHK; ++c) {
    const int cb = c & 1, nb = cb ^ 1;

    // ---------------- phase 1 (reads of raw staging buffers) ----------------
    if (c > 0) {   // flush previous chunk's y half (coalesced b128)
      const int tf = tid >> 2, p8 = (tid & 3) * 8;
      bf16x8 vy = *(const bf16x8*)&yO[nb][tf * 40 + p8];
      *(bf16x8*)(ybase + (size_t)((c - 1) * CH + tf) * DINNER + p8) = vy;
    }

    // B^T repack from row-major Braw2 (128 threads, 4 gathers each)
    {
      const int n = tid;                    // 0..127
#pragma unroll
      for (int e = 0; e < 4; ++e) {         // qp = s>>3
        bf16x8 v;
#pragma unroll
        for (int j = 0; j < 8; ++j) v[j] = Braw2[(e * 8 + j) * 128 + n];
        *(bf16x8*)&BTf[((n >> 4) * 64 + e * 16 + (n & 15)) * 8] = v;
      }
    }

    // C frags (both waves); G tiles: w0 -> (0,0),(1,1); w1 -> (1,0)
    bf16x8 Cf0[4], Cf1[4];
#pragma unroll
    for (int kk = 0; kk < 4; ++kk) {
      Cf0[kk] = *(const bf16x8*)&Crawf[(kk * 64 + lane) * 8];
      Cf1[kk] = *(const bf16x8*)&Crawf[((4 + kk) * 64 + lane) * 8];
    }
    {
      const int nG = (w == 0) ? 2 : 1;
      for (int g = 0; g < nG; ++g) {
        const int tt = (w == 0) ? g : 1;
        const int ss = (w == 0) ? g : 0;
        f32x4 G = {};
#pragma unroll
        for (int kk = 0; kk < 4; ++kk) {
          bf16x8 Bq = *(const bf16x8*)&Brawf[((ss * 4 + kk) * 64 + lane) * 8];
          G = __builtin_amdgcn_mfma_f32_16x16x32_bf16(tt ? Cf1[kk] : Cf0[kk], Bq, G, 0, 0, 0);
        }
        const int sgl = ss * 16 + l15;
        const float sdt = ddL[cb][sgl];
        const float scd = ddL[cb][32 + sgl];
#pragma unroll
        for (int r = 0; r < 4; ++r) {
          const int t0 = q * 4 + r;
          float v = G[r] * sdt * __expf(ddL[cb][32 + tt * 16 + t0] - scd);
          if (tt == ss) {
            if (t0 < l15) v = 0.f;
            else if (t0 == l15) v += Dh;       // absorb D*x into S diagonal
          }
          SL[(tt * 64 + (ss * 2 + (l15 >> 3)) * 16 + t0) * 8 + (l15 & 7)] = (__bf16)v;
        }
      }
    }
    __syncthreads();   // barrier A — raw-buffer reads complete block-wide

    // ---------------- phase 2 ----------------
    if (c + 1 < NCHK) issue(c + 1, nb);       // single-buffer overwrite: safe
    bf16x8 xt_n;
    if (c + 1 < NCHK) xt_n = load_xt(c + 1);

    // y_intra: y^T[p][t] = X^T @ S^T
    f32x4 accy0 = {}, accy1 = {};
    {
      bf16x8 S0 = *(const bf16x8*)&SL[(lane) * 8];
      bf16x8 S1 = *(const bf16x8*)&SL[(64 + lane) * 8];
      accy0 = __builtin_amdgcn_mfma_f32_16x16x32_bf16(xt, S0, accy0, 0, 0, 0);
      accy1 = __builtin_amdgcn_mfma_f32_16x16x32_bf16(xt, S1, accy1, 0, 0, 0);
    }
    // y_inter: (H_prev @ C^T) .* P_t
    {
      f32x4 ai0 = {}, ai1 = {};
#pragma unroll
      for (int kk = 0; kk < 4; ++kk) {
        bf16x8 Hf = *(const bf16x8*)&HL[w][(kk * 64 + lane) * 8];
        ai0 = __builtin_amdgcn_mfma_f32_16x16x32_bf16(Hf, Cf0[kk], ai0, 0, 0, 0);
        ai1 = __builtin_amdgcn_mfma_f32_16x16x32_bf16(Hf, Cf1[kk], ai1, 0, 0, 0);
      }
      const float P0 = ddL[cb][96 + l15], P1 = ddL[cb][96 + 16 + l15];
      accy0 = accy0 + ai0 * P0;
      accy1 = accy1 + ai1 * P1;
    }
    // H update: H = atot*H + (X.*W)^T @ B
    {
      const float atot = ddL[cb][96 + 31];
      bf16x8 xw;
#pragma unroll
      for (int j = 0; j < 8; ++j)
        xw[j] = (__bf16)((float)xt[j] * ddL[cb][64 + q * 8 + j]);
#pragma unroll
      for (int nt = 0; nt < 8; ++nt) {
        bf16x8 Bt = *(const bf16x8*)&BTf[(nt * 64 + lane) * 8];
        accH[nt] = accH[nt] * atot;
        accH[nt] = __builtin_amdgcn_mfma_f32_16x16x32_bf16(xw, Bt, accH[nt], 0, 0, 0);
      }
#pragma unroll
      for (int nt = 0; nt < 8; ++nt)
#pragma unroll
        for (int r = 0; r < 4; ++r) {
          const int n = nt * 16 + l15;
          HL[w][((n >> 5) * 64 + ((n & 31) >> 3) * 16 + q * 4 + r) * 8 + (n & 7)] =
              (__bf16)accH[nt][r];
        }
    }
    // stage y half-chunk
#pragma unroll
    for (int r = 0; r < 4; ++r) {
      const int p = w * 16 + q * 4 + r;
      yO[cb][l15 * 40 + p]        = (__bf16)accy0[r];
      yO[cb][(16 + l15) * 40 + p] = (__bf16)accy1[r];
    }
    xt = xt_n;
    __syncthreads();   // barrier B (drains async staging for c+1)
  }
  {  // final flush
    const int tf = tid >> 2, p8 = (tid & 3) * 8;
    bf16x8 vy = *(const bf16x8*)&yO[(NCHK - 1) & 1][tf * 40 + p8];
    *(bf16x8*)(ybase + (size_t)((NCHK - 1) * CH + tf) * DINNER + p8) = vy;
  }
}

// ---------------------------------------------------------------------------
// Gate (y * silu(z)) + RMSNorm per direction + average-with-flip -> bf16.
// ---------------------------------------------------------------------------
__global__ __launch_bounds__(256) void k_gate_combine(
    const __bf16* __restrict__ zxb, const unsigned short* __restrict__ y,
    const float* __restrict__ nw_f, const float* __restrict__ nw_r,
    const int* __restrict__ lengths, unsigned short* __restrict__ comb) {
  const int bx = blockIdx.x;            // b*SEQ + l
  const int b = bx >> 10, l = bx & 1023;
  const int tid = threadIdx.x;
  const int len = lengths[b];
  const int pos = (l < len) ? (len - 1 - l) : l;
  const __bf16* z = zxb + (size_t)bx * DPROJ_PAD;
  const unsigned short* yf = y + ((size_t)b * SEQ + l) * DINNER;
  const unsigned short* yr = y + ((size_t)(BSZ + b) * SEQ + pos) * DINNER;

  float gf[8], gr[8];
  float sf = 0.f, sr = 0.f;
#pragma unroll
  for (int k = 0; k < 8; ++k) {
    int c = tid + k * 256;
    float zz = (float)z[c];
    float sz = zz / (1.f + __expf(-zz));
    float vf = bf2f(yf[c]) * sz;
    float vr = bf2f(yr[c]) * sz;
    gf[k] = vf; gr[k] = vr;
    sf += vf * vf; sr += vr * vr;
  }
  for (int o = 32; o > 0; o >>= 1) { sf += __shfl_down(sf, o); sr += __shfl_down(sr, o); }
  __shared__ float red[8];
  if ((tid & 63) == 0) { red[tid >> 6] = sf; red[4 + (tid >> 6)] = sr; }
  __syncthreads();
  sf = red[0] + red[1] + red[2] + red[3];
  sr = red[4] + red[5] + red[6] + red[7];
  float rf = rsqrtf(sf * (1.f / DINNER) + EPSF);
  float rr = rsqrtf(sr * (1.f / DINNER) + EPSF);
#pragma unroll
  for (int k = 0; k < 8; ++k) {
    int c = tid + k * 256;
    float o = 0.5f * (gf[k] * rf * nw_f[c] + gr[k] * rr * nw_r[c]);
    comb[(size_t)bx * DINNER + c] = f2bf(o);
  }
}

// ---------------------------------------------------------------------------
extern "C" void kernel_launch(void* const* d_in, const int* in_sizes, int n_in,
                              void* d_out, int out_size, void* d_ws, size_t ws_size,
                              hipStream_t stream) {
  const float* hidden      = (const float*)d_in[0];
  const unsigned char* msk = (const unsigned char*)d_in[1];
  const float* in_proj_w   = (const float*)d_in[2];
  const float* out_proj_w  = (const float*)d_in[3];
  const float* conv_w_f    = (const float*)d_in[4];
  const float* conv_b_f    = (const float*)d_in[5];
  const float* dt_bias_f   = (const float*)d_in[6];
  const float* A_log_f     = (const float*)d_in[7];
  const float* D_f         = (const float*)d_in[8];
  const float* norm_w_f    = (const float*)d_in[9];
  const float* conv_w_r    = (const float*)d_in[10];
  const float* conv_b_r    = (const float*)d_in[11];
  const float* dt_bias_r   = (const float*)d_in[12];
  const float* A_log_r     = (const float*)d_in[13];
  const float* D_r         = (const float*)d_in[14];
  const float* norm_w_r    = (const float*)d_in[15];
  float* outF = (float*)d_out;

  char* ws = (char*)d_ws;
  size_t o_w1b  = 0;                         // bf16 [4480][1024]
  size_t o_w2b  = o_w1b  + 9175040;          // bf16 [1024][2048]
  size_t o_hb   = o_w2b  + 4194304;          // bf16 [4096][1024]
  size_t o_zx   = o_hb   + 8388608;          // bf16 [4096][4480]
  size_t o_xb   = o_zx   + 36700160;         // bf16 [2][4096][2304]
  size_t o_dd   = o_xb   + 37748736;         // f32  [8192][128]
  size_t o_y    = o_dd   + 4194304;          // bf16 [2][4096][2048]
  size_t o_comb = o_y    + 33554432;         // bf16 [4096][2048]
  size_t o_outp = o_comb + 16777216;         // bf16 [4096][1024]
  size_t o_len  = o_outp + 8388608;          // int  [4]

  unsigned short* W1b  = (unsigned short*)(ws + o_w1b);
  unsigned short* W2b  = (unsigned short*)(ws + o_w2b);
  unsigned short* hb   = (unsigned short*)(ws + o_hb);
  __bf16*         zxb  = (__bf16*)(ws + o_zx);
  __bf16*         xb   = (__bf16*)(ws + o_xb);
  float*          ddg  = (float*)(ws + o_dd);
  unsigned short* yB   = (unsigned short*)(ws + o_y);
  unsigned short* comb = (unsigned short*)(ws + o_comb);
  unsigned short* outp = (unsigned short*)(ws + o_outp);
  int*            lens = (int*)(ws + o_len);

  k_convert<<<(W1N + W2N) / 256, 256, 0, stream>>>(in_proj_w, out_proj_w, W1b, W2b);
  k_lengths<<<BSZ, 256, 0, stream>>>(msk, lens);

  k_ln_bf16<<<NTOK, 256, 0, stream>>>(hidden, hb);

  k_gemm_bt_h<<<dim3(NTOK / 128, DPROJ_PAD / 128), 256, 0, stream>>>(
      hb, W1b, (unsigned short*)zxb, DMODEL, DMODEL, DMODEL, DPROJ_PAD);

  k_conv<<<2 * BSZ * (SEQ / 16), 256, 0, stream>>>(
      zxb, conv_w_f, conv_b_f, conv_w_r, conv_b_r, lens, xb);

  k_dtprep<<<1024, 256, 0, stream>>>(
      zxb, dt_bias_f, dt_bias_r, A_log_f, A_log_r, lens, ddg);

  k_scan<<<2 * 2 * BSZ * NHEADS, 128, 0, stream>>>(xb, ddg, D_f, D_r, yB);

  k_gate_combine<<<NTOK, 256, 0, stream>>>(zxb, yB, norm_w_f, norm_w_r, lens, comb);

  k_gemm_bt_h<<<dim3(NTOK / 128, DMODEL / 128), 256, 0, stream>>>(
      comb, W2b, outp, DINNER, DINNER, DINNER, DMODEL);

  k_ln_out<<<NTOK, 256, 0, stream>>>(outp, outF);

  (void)in_sizes; (void)n_in; (void)out_size; (void)ws_size;
}

// Round 8
// 303.828 us; speedup vs baseline: 1.1015x; 1.1015x over previous
//
#include <hip/hip_runtime.h>

// ---------------------------------------------------------------------------
// BiMamba2 (D_MODEL=1024, D_INNER=2048, NHEADS=32, HEADDIM=64, D_STATE=128,
// D_CONV=4, B=4, L=1024).  Pipeline:
//   prep(convert+ln1+lengths) -> GEMM1 -> conv -> dtprep -> chunked MFMA scan
//   -> gate+RMS+combine -> GEMM2 -> ln2
//
// R15: k_scan frozen at the R7 structure (60.3us; R8-R14 showed every
// schedule perturbation regresses).  This round applies G13 vectorization
// to the auxiliary kernels and cuts launch count:
//   - k_conv: thread owns 8 consecutive channels (bf16x8 load/store) + 1
//     tail channel; 2 loads/row instead of 9 scalar.  Bit-identical math.
//   - k_gate_combine: c = tid*8+j mapping; bf16x8/float4 loads, bf16x8
//     store (partial-sum order changes -> epsilon in rf/rr only).
//   - k_prep = convert + ln_bf16 + lengths merged (independent work items,
//     block-uniform branch on blockIdx): 10 -> 8 dispatches.
// ---------------------------------------------------------------------------

#define BSZ 4
#define SEQ 1024
#define DMODEL 1024
#define DINNER 2048
#define NHEADS 32
#define HEADDIM 64
#define DSTATE 128
#define CONVDIM 2304            // DINNER + 2*DSTATE
#define DPROJ 4384              // 2*DINNER + 2*DSTATE + NHEADS
#define DPROJ_PAD 4480          // padded to multiple of 128
#define NTOK (BSZ*SEQ)          // 4096
#define EPSF 1e-5f
#define CH 32                   // scan chunk length
#define NCHK (SEQ/CH)           // 32 chunks

typedef float f32x4 __attribute__((ext_vector_type(4)));
typedef __bf16 bf16x8 __attribute__((ext_vector_type(8)));

__device__ __forceinline__ unsigned short f2bf(float f) {
  unsigned int x = __float_as_uint(f);
  unsigned int r = (x + 0x7fffu + ((x >> 16) & 1u)) >> 16;
  return (unsigned short)r;
}
__device__ __forceinline__ float bf2f(unsigned short u) {
  return __uint_as_float(((unsigned int)u) << 16);
}

__device__ __forceinline__ void async_load16(const void* g, void* l) {
  __builtin_amdgcn_global_load_lds(
      (const __attribute__((address_space(1))) void*)g,
      (__attribute__((address_space(3))) void*)l, 16, 0, 0);
}

// ---------------------------------------------------------------------------
// Merged prep: weight conversion + LayerNorm1 (fp32 -> bf16) + lengths.
// Grid = CONV_BLKS + NTOK + BSZ blocks of 256; branch is block-uniform.
// ---------------------------------------------------------------------------
#define W1N (DPROJ_PAD * DMODEL)
#define W2N (DMODEL * DINNER)
#define CONV_BLKS ((W1N + W2N) / 256)     // 26112

__global__ __launch_bounds__(256) void k_prep(
    const float* __restrict__ hidden, const unsigned char* __restrict__ msk,
    const float* __restrict__ w1, const float* __restrict__ w2,
    unsigned short* __restrict__ o1, unsigned short* __restrict__ o2,
    unsigned short* __restrict__ hb, int* __restrict__ lengths) {
  const int bid = blockIdx.x;
  const int tid = threadIdx.x;
  __shared__ float redf[8];
  __shared__ int redi[4];

  if (bid < CONV_BLKS) {
    // ---- weight conversion ----
    int idx = bid * 256 + tid;
    if (idx < W1N) {
      int row = idx >> 10, col = idx & 1023;
      float v = (row < DPROJ) ? w1[(size_t)row * DMODEL + col] : 0.f;
      o1[idx] = f2bf(v);
    } else {
      int k = idx - W1N;
      o2[k] = f2bf(w2[k]);
    }
  } else if (bid < CONV_BLKS + NTOK) {
    // ---- LayerNorm (1024 wide, fp32 in) -> bf16 ----
    int row = bid - CONV_BLKS;
    float4 v = ((const float4*)(hidden + (size_t)row * DMODEL))[tid];
    float s = v.x + v.y + v.z + v.w;
    float ss = v.x * v.x + v.y * v.y + v.z * v.z + v.w * v.w;
    for (int o = 32; o > 0; o >>= 1) { s += __shfl_down(s, o); ss += __shfl_down(ss, o); }
    if ((tid & 63) == 0) { redf[tid >> 6] = s; redf[4 + (tid >> 6)] = ss; }
    __syncthreads();
    s = redf[0] + redf[1] + redf[2] + redf[3];
    ss = redf[4] + redf[5] + redf[6] + redf[7];
    float mu = s * (1.f / DMODEL);
    float var = ss * (1.f / DMODEL) - mu * mu;
    float rs = rsqrtf(var + EPSF);
    ushort4 o;
    o.x = f2bf((v.x - mu) * rs); o.y = f2bf((v.y - mu) * rs);
    o.z = f2bf((v.z - mu) * rs); o.w = f2bf((v.w - mu) * rs);
    ((ushort4*)(hb + (size_t)row * DMODEL))[tid] = o;
  } else {
    // ---- lengths ----
    int b = bid - CONV_BLKS - NTOK;
    int cnt = 0;
    for (int k = 0; k < 4; ++k)
      cnt += (msk[(size_t)b * SEQ + tid + k * 256] == 0) ? 1 : 0;
    for (int o = 32; o > 0; o >>= 1) cnt += __shfl_down(cnt, o);
    if ((tid & 63) == 0) redi[tid >> 6] = cnt;
    __syncthreads();
    if (tid == 0) lengths[b] = redi[0] + redi[1] + redi[2] + redi[3];
  }
}

// LayerNorm (1024 wide, bf16 in) -> fp32 out (final)
__global__ __launch_bounds__(256) void k_ln_out(const unsigned short* __restrict__ in,
                                                float* __restrict__ out) {
  int row = blockIdx.x, tid = threadIdx.x;
  ushort4 u = ((const ushort4*)(in + (size_t)row * DMODEL))[tid];
  float4 v;
  v.x = bf2f(u.x); v.y = bf2f(u.y); v.z = bf2f(u.z); v.w = bf2f(u.w);
  float s = v.x + v.y + v.z + v.w;
  float ss = v.x * v.x + v.y * v.y + v.z * v.z + v.w * v.w;
  for (int o = 32; o > 0; o >>= 1) { s += __shfl_down(s, o); ss += __shfl_down(ss, o); }
  __shared__ float red[8];
  if ((tid & 63) == 0) { red[tid >> 6] = s; red[4 + (tid >> 6)] = ss; }
  __syncthreads();
  s = red[0] + red[1] + red[2] + red[3];
  ss = red[4] + red[5] + red[6] + red[7];
  float mu = s * (1.f / DMODEL);
  float var = ss * (1.f / DMODEL) - mu * mu;
  float rs = rsqrtf(var + EPSF);
  float4 o;
  o.x = (v.x - mu) * rs; o.y = (v.y - mu) * rs;
  o.z = (v.z - mu) * rs; o.w = (v.w - mu) * rs;
  ((float4*)(out + (size_t)row * DMODEL))[tid] = o;
}

// ---------------------------------------------------------------------------
// bf16 MFMA GEMM (B^T form): C[M,N] = A[M,K] * B[N,K]^T, bf16 out.
// BK=64 as two stacked BK=32 half-buffers: 32 MFMAs per barrier pair.
// ---------------------------------------------------------------------------
__global__ __launch_bounds__(256) void k_gemm_bt_h(const unsigned short* __restrict__ A,
                                                   const unsigned short* __restrict__ B,
                                                   unsigned short* __restrict__ C,
                                                   int K, int lda, int ldb, int ldc) {
  __shared__ unsigned short Asm[2][128 * 32];
  __shared__ unsigned short Bsm[2][128 * 32];
  const int tid = threadIdx.x;
  const int lane = tid & 63;
  const int w = tid >> 6;
  const int wm = w >> 1, wn = w & 1;
  const long m0 = (long)blockIdx.x * 128;
  const long n0 = (long)blockIdx.y * 128;

  const int sr = lane >> 2;
  const int sc = (lane & 3) * 8;
  const unsigned short* gA0 = A + (m0 + (w * 2 + 0) * 16 + sr) * (long)lda + sc;
  const unsigned short* gA1 = A + (m0 + (w * 2 + 1) * 16 + sr) * (long)lda + sc;
  const unsigned short* gB0 = B + (n0 + (w * 2 + 0) * 16 + sr) * (long)ldb + sc;
  const unsigned short* gB1 = B + (n0 + (w * 2 + 1) * 16 + sr) * (long)ldb + sc;

  f32x4 acc[4][4] = {};
  const int q8 = (lane >> 4) * 8;
  const int r16 = lane & 15;

  for (int k0 = 0; k0 < K; k0 += 64) {
#pragma unroll
    for (int h = 0; h < 2; ++h) {
      const int ko = k0 + h * 32;
      async_load16(gA0 + ko, Asm[h] + (w * 2 + 0) * 512);
      async_load16(gA1 + ko, Asm[h] + (w * 2 + 1) * 512);
      async_load16(gB0 + ko, Bsm[h] + (w * 2 + 0) * 512);
      async_load16(gB1 + ko, Bsm[h] + (w * 2 + 1) * 512);
    }
    __syncthreads();
#pragma unroll
    for (int h = 0; h < 2; ++h) {
      bf16x8 af[4], bfr[4];
#pragma unroll
      for (int i = 0; i < 4; ++i)
        af[i] = *reinterpret_cast<const bf16x8*>(Asm[h] + (wm * 64 + i * 16 + r16) * 32 + q8);
#pragma unroll
      for (int j = 0; j < 4; ++j)
        bfr[j] = *reinterpret_cast<const bf16x8*>(Bsm[h] + (wn * 64 + j * 16 + r16) * 32 + q8);
#pragma unroll
      for (int i = 0; i < 4; ++i)
#pragma unroll
        for (int j = 0; j < 4; ++j)
          acc[i][j] = __builtin_amdgcn_mfma_f32_16x16x32_bf16(af[i], bfr[j], acc[i][j], 0, 0, 0);
    }
    __syncthreads();
  }
  const int q = lane >> 4, cn = lane & 15;
#pragma unroll
  for (int i = 0; i < 4; ++i)
#pragma unroll
    for (int j = 0; j < 4; ++j) {
      long crow = m0 + wm * 64 + i * 16 + q * 4;
      long ccol = n0 + wn * 64 + j * 16 + cn;
#pragma unroll
      for (int r = 0; r < 4; ++r)
        C[(crow + r) * (long)ldc + ccol] = f2bf(acc[i][j][r]);
    }
}

// ---------------------------------------------------------------------------
// Depthwise causal conv (width 4) + SiLU over xBC slice (bf16 in) -> bf16.
// R15: vectorized — thread owns 8 consecutive channels (tid*8, bf16x8
// loads/stores) + 1 tail channel (2048+tid).  Same per-channel FLOP order
// as the scalar version -> bit-identical output.
// ---------------------------------------------------------------------------
__global__ __launch_bounds__(256) void k_conv(
    const __bf16* __restrict__ zxb,
    const float* __restrict__ cw_f, const float* __restrict__ cb_f,
    const float* __restrict__ cw_r, const float* __restrict__ cb_r,
    const int* __restrict__ lengths,
    __bf16* __restrict__ xb) {
  const int bx = blockIdx.x;                // db*64 + tg
  const int tg = bx & 63;
  const int db = bx >> 6;
  const int b = db & 3;
  const int dir = db >> 2;
  const int tid = threadIdx.x;
  const int len = lengths[b];
  const int t0 = tg * 16;

  const float* cw = dir ? cw_r : cw_f;
  const float* cb = dir ? cb_r : cb_f;

  const int cA = tid * 8;          // 8 consecutive channels in [0,2048)
  const int cB = 2048 + tid;       // tail channel in [2048,2304)

  float wA0[8], wA1[8], wA2[8], wA3[8], bA[8];
  float rA0[8], rA1[8], rA2[8], rA3[8];
#pragma unroll
  for (int j = 0; j < 8; ++j) {
    float4 w4 = *(const float4*)(cw + (size_t)(cA + j) * 4);
    wA0[j] = w4.x; wA1[j] = w4.y; wA2[j] = w4.z; wA3[j] = w4.w;
    bA[j] = cb[cA + j];
    rA0[j] = 0.f; rA1[j] = 0.f; rA2[j] = 0.f;
  }
  float4 wB4 = *(const float4*)(cw + (size_t)cB * 4);
  float bB = cb[cB];
  float rB0 = 0.f, rB1 = 0.f, rB2 = 0.f, rB3;

  auto rowptr = [&](int tt) -> const __bf16* {
    int s = dir ? ((tt < len) ? (len - 1 - tt) : tt) : tt;
    return zxb + ((size_t)b * SEQ + s) * DPROJ_PAD + DINNER;
  };
  auto loadA = [&](const __bf16* rp, float* dst) {
    bf16x8 v = *(const bf16x8*)(rp + cA);
#pragma unroll
    for (int j = 0; j < 8; ++j) dst[j] = (float)v[j];
  };

  if (t0 >= 3) {
    const __bf16* ra = rowptr(t0 - 3);
    const __bf16* rb = rowptr(t0 - 2);
    const __bf16* rc = rowptr(t0 - 1);
    loadA(ra, rA0); loadA(rb, rA1); loadA(rc, rA2);
    rB0 = (float)ra[cB]; rB1 = (float)rb[cB]; rB2 = (float)rc[cB];
  }
  {
    const __bf16* rp = rowptr(t0);
    loadA(rp, rA3);
    rB3 = (float)rp[cB];
  }
  for (int j = 0; j < 16; ++j) {
    float r4A[8] = {};
    float r4B = 0.f;
    if (j < 15) {
      const __bf16* rp = rowptr(t0 + j + 1);
      loadA(rp, r4A);
      r4B = (float)rp[cB];
    }
    __bf16* orow = xb + ((size_t)db * SEQ + t0 + j) * CONVDIM;
    bf16x8 ov;
#pragma unroll
    for (int k = 0; k < 8; ++k) {
      float acc = bA[k];
      acc = fmaf(wA0[k], rA0[k], acc);
      acc = fmaf(wA1[k], rA1[k], acc);
      acc = fmaf(wA2[k], rA2[k], acc);
      acc = fmaf(wA3[k], rA3[k], acc);
      float sig = 1.f / (1.f + __expf(-acc));
      ov[k] = (__bf16)(acc * sig);
      rA0[k] = rA1[k]; rA1[k] = rA2[k]; rA2[k] = rA3[k]; rA3[k] = r4A[k];
    }
    *(bf16x8*)(orow + cA) = ov;
    {
      float acc = bB;
      acc = fmaf(wB4.x, rB0, acc);
      acc = fmaf(wB4.y, rB1, acc);
      acc = fmaf(wB4.z, rB2, acc);
      acc = fmaf(wB4.w, rB3, acc);
      float sig = 1.f / (1.f + __expf(-acc));
      orow[cB] = (__bf16)(acc * sig);
      rB0 = rB1; rB1 = rB2; rB2 = rB3; rB3 = r4B;
    }
  }
}

// ---------------------------------------------------------------------------
// dt/decay table precompute.  One 32-lane group per (db,h,chunk): 8192
// groups.  Layout ddg[task][128]: dt / cd=A*cum / W / P.
// ---------------------------------------------------------------------------
__global__ __launch_bounds__(256) void k_dtprep(
    const __bf16* __restrict__ zxb,
    const float* __restrict__ dtb_f, const float* __restrict__ dtb_r,
    const float* __restrict__ al_f, const float* __restrict__ al_r,
    const int* __restrict__ lengths, float* __restrict__ ddg) {
  const int task = (blockIdx.x * 256 + threadIdx.x) >> 5;  // (db*32+h)*32+chunk
  const int l32 = threadIdx.x & 31;
  const int chunk = task & 31, hh = (task >> 5) & 31, db = task >> 10;
  const int b = db & 3, dir = db >> 2;
  const int len = lengths[b];
  const float dtbv = (dir ? dtb_r : dtb_f)[hh];
  const float Ah = -__expf((dir ? al_r : al_f)[hh]);
  const int s = chunk * 32 + l32;
  const int sf = dir ? ((s < len) ? (len - 1 - s) : s) : s;
  float raw = (float)zxb[(size_t)(b * SEQ + sf) * DPROJ_PAD + DINNER + CONVDIM + hh] + dtbv;
  float d = (raw > 20.f) ? raw : log1pf(__expf(raw));
  float cum = d;
#pragma unroll
  for (int o = 1; o < 32; o <<= 1) {
    float v = __shfl_up(cum, o, 32);
    if (l32 >= o) cum += v;
  }
  float cum31 = __shfl(cum, 31, 32);
  float* o = ddg + (size_t)task * 128;
  o[l32]      = d;
  o[32 + l32] = Ah * cum;
  o[64 + l32] = d * __expf(Ah * (cum31 - cum));
  o[96 + l32] = __expf(Ah * cum);
}

// ---------------------------------------------------------------------------
// Chunked MFMA selective scan, frag-linear LDS (R7 structure, frozen).
// Single-buffered raw staging, 2 blocks/CU.
// ---------------------------------------------------------------------------
__global__ __launch_bounds__(256, 2) void k_scan(
    const __bf16* __restrict__ xb, const float* __restrict__ ddg,
    const float* __restrict__ D_f, const float* __restrict__ D_r,
    unsigned short* __restrict__ y) {
  __shared__ __bf16 Crawf[4096];      // C frag-linear, 8 tiles (tt,kk)
  __shared__ __bf16 Brawf[4096];      // B frag-linear (B-as-rows x k=n)
  __shared__ __bf16 Braw2[4096];      // B row-major [s][n] (for BT repack)
  __shared__ __bf16 BTf[4096];        // B^T frag-linear, 8 tiles (ng)
  __shared__ float  ddL[2][128];      // dt/cd/W/P tables (double)
  __shared__ __bf16 SL[1024];         // S frag-linear, 2 tiles (t-halves)
  __shared__ __bf16 HL[4][2048];      // per-wave H frag-linear, 4 tiles (kk)
  __shared__ __bf16 yO[2][32 * 72];   // y chunk [t][p], stride 72 (double)

  const int bx = blockIdx.x;          // db*32 + h
  const int h = bx & 31;
  const int db = bx >> 5;
  const int dir = db >> 2;
  const int tid = threadIdx.x;
  const int lane = tid & 63;
  const int w = tid >> 6;
  const int l15 = lane & 15;
  const int q = lane >> 4;

  const float Dh = (dir ? D_r : D_f)[h];
  const __bf16* xbase = xb + (size_t)db * SEQ * CONVDIM;
  const float* ddbase = ddg + (size_t)bx * NCHK * 128;
  unsigned short* ybase = y + (size_t)db * SEQ * DINNER + h * HEADDIM;

  for (int i = lane; i < 2048; i += 64) HL[w][i] = (__bf16)0.f;
  for (int i = tid; i < 1024; i += 256) SL[i] = (__bf16)0.f;

  f32x4 accH[8] = {};

  auto issue = [&](int c, int nb) {
    const __bf16* xr = xbase + (size_t)c * CH * CONVDIM;
#pragma unroll
    for (int k = 0; k < 2; ++k) {
      const int idx = w * 2 + k;              // 0..7
      const int P = idx * 64 + lane;
      const int tt = P >> 8, kk = (P >> 6) & 3, qq = (P >> 4) & 3, ll = P & 15;
      const __bf16* gB = xr + (size_t)(tt * 16 + ll) * CONVDIM + DINNER + kk * 32 + qq * 8;
      async_load16(gB, &Brawf[idx * 512]);
      async_load16(gB + 128, &Crawf[idx * 512]);
      const int s = P >> 4, n8 = P & 15;
      const __bf16* g2 = xr + (size_t)s * CONVDIM + DINNER + n8 * 8;
      async_load16(g2, &Braw2[idx * 512]);
    }
    if (w == 3 && lane < 32)
      async_load16(ddbase + (size_t)c * 128 + lane * 4, &ddL[nb][0]);
  };

  auto load_xt = [&](int c) {
    bf16x8 v;
    const __bf16* gx = xbase + (size_t)(c * CH + q * 8) * CONVDIM + h * HEADDIM + w * 16 + l15;
#pragma unroll
    for (int j = 0; j < 8; ++j) v[j] = gx[(size_t)j * CONVDIM];
    return v;
  };

  issue(0, 0);
  bf16x8 xt = load_xt(0);
  __syncthreads();

  for (int c = 0; c < NCHK; ++c) {
    const int cb = c & 1, nb = cb ^ 1;

    // ---------------- phase 1 (reads of raw staging buffers) ----------------
    if (c > 0) {   // flush previous chunk's y (coalesced)
      const int tf = tid >> 3, p8 = (tid & 7) * 8;
      bf16x8 vy = *(const bf16x8*)&yO[nb][tf * 72 + p8];
      *(bf16x8*)(ybase + (size_t)((c - 1) * CH + tf) * DINNER + p8) = vy;
    }

    // B^T repack from row-major Braw2
    {
      const int n = tid & 127, sg = tid >> 7;
#pragma unroll
      for (int e = 0; e < 2; ++e) {
        const int qp = sg * 2 + e;            // q' = s>>3
        bf16x8 v;
#pragma unroll
        for (int j = 0; j < 8; ++j) v[j] = Braw2[(qp * 8 + j) * 128 + n];
        *(bf16x8*)&BTf[((n >> 4) * 64 + qp * 16 + (n & 15)) * 8] = v;
      }
    }

    // C frags (all waves); G quadrant + mask (waves 0-2)
    bf16x8 Cf0[4], Cf1[4];
#pragma unroll
    for (int kk = 0; kk < 4; ++kk) {
      Cf0[kk] = *(const bf16x8*)&Crawf[(kk * 64 + lane) * 8];
      Cf1[kk] = *(const bf16x8*)&Crawf[((4 + kk) * 64 + lane) * 8];
    }
    if (w < 3) {
      const int tt = (w == 0) ? 0 : 1;
      const int ss = (w == 2) ? 1 : 0;
      f32x4 G = {};
#pragma unroll
      for (int kk = 0; kk < 4; ++kk) {
        bf16x8 Bq = *(const bf16x8*)&Brawf[((ss * 4 + kk) * 64 + lane) * 8];
        G = __builtin_amdgcn_mfma_f32_16x16x32_bf16(tt ? Cf1[kk] : Cf0[kk], Bq, G, 0, 0, 0);
      }
      const int sgl = ss * 16 + l15;
      const float sdt = ddL[cb][sgl];
      const float scd = ddL[cb][32 + sgl];
#pragma unroll
      for (int r = 0; r < 4; ++r) {
        const int t0 = q * 4 + r;
        float v = G[r] * sdt * __expf(ddL[cb][32 + tt * 16 + t0] - scd);
        if (tt == ss) {
          if (t0 < l15) v = 0.f;
          else if (t0 == l15) v += Dh;         // absorb D*x into S diagonal
        }
        SL[(tt * 64 + (ss * 2 + (l15 >> 3)) * 16 + t0) * 8 + (l15 & 7)] = (__bf16)v;
      }
    }
    __syncthreads();   // barrier A — raw-buffer reads complete block-wide

    // ---------------- phase 2 ----------------
    if (c + 1 < NCHK) issue(c + 1, nb);       // safe: single-buffer overwrite
    bf16x8 xt_n;
    if (c + 1 < NCHK) xt_n = load_xt(c + 1);

    // y_intra: y^T[p][t] = X^T @ S^T
    f32x4 accy0 = {}, accy1 = {};
    {
      bf16x8 S0 = *(const bf16x8*)&SL[(lane) * 8];
      bf16x8 S1 = *(const bf16x8*)&SL[(64 + lane) * 8];
      accy0 = __builtin_amdgcn_mfma_f32_16x16x32_bf16(xt, S0, accy0, 0, 0, 0);
      accy1 = __builtin_amdgcn_mfma_f32_16x16x32_bf16(xt, S1, accy1, 0, 0, 0);
    }
    // y_inter: (H_prev @ C^T) .* P_t
    {
      f32x4 ai0 = {}, ai1 = {};
#pragma unroll
      for (int kk = 0; kk < 4; ++kk) {
        bf16x8 Hf = *(const bf16x8*)&HL[w][(kk * 64 + lane) * 8];
        ai0 = __builtin_amdgcn_mfma_f32_16x16x32_bf16(Hf, Cf0[kk], ai0, 0, 0, 0);
        ai1 = __builtin_amdgcn_mfma_f32_16x16x32_bf16(Hf, Cf1[kk], ai1, 0, 0, 0);
      }
      const float P0 = ddL[cb][96 + l15], P1 = ddL[cb][96 + 16 + l15];
      accy0 = accy0 + ai0 * P0;
      accy1 = accy1 + ai1 * P1;
    }
    // H update: H = atot*H + (X.*W)^T @ B
    {
      const float atot = ddL[cb][96 + 31];
      bf16x8 xw;
#pragma unroll
      for (int j = 0; j < 8; ++j)
        xw[j] = (__bf16)((float)xt[j] * ddL[cb][64 + q * 8 + j]);
#pragma unroll
      for (int nt = 0; nt < 8; ++nt) {
        bf16x8 Bt = *(const bf16x8*)&BTf[(nt * 64 + lane) * 8];
        accH[nt] = accH[nt] * atot;
        accH[nt] = __builtin_amdgcn_mfma_f32_16x16x32_bf16(xw, Bt, accH[nt], 0, 0, 0);
      }
#pragma unroll
      for (int nt = 0; nt < 8; ++nt)
#pragma unroll
        for (int r = 0; r < 4; ++r) {
          const int n = nt * 16 + l15;
          HL[w][((n >> 5) * 64 + ((n & 31) >> 3) * 16 + q * 4 + r) * 8 + (n & 7)] =
              (__bf16)accH[nt][r];
        }
    }
    // stage y chunk
#pragma unroll
    for (int r = 0; r < 4; ++r) {
      const int p = w * 16 + q * 4 + r;
      yO[cb][l15 * 72 + p]        = (__bf16)accy0[r];
      yO[cb][(16 + l15) * 72 + p] = (__bf16)accy1[r];
    }
    xt = xt_n;
    __syncthreads();   // barrier B (drains async staging for c+1)
  }
  {  // final flush
    const int tf = tid >> 3, p8 = (tid & 7) * 8;
    bf16x8 vy = *(const bf16x8*)&yO[(NCHK - 1) & 1][tf * 72 + p8];
    *(bf16x8*)(ybase + (size_t)((NCHK - 1) * CH + tf) * DINNER + p8) = vy;
  }
}

// ---------------------------------------------------------------------------
// Gate (y * silu(z)) + RMSNorm per direction + average-with-flip -> bf16.
// R15: vectorized — c = tid*8+j; bf16x8/float4 loads, bf16x8 store.
// ---------------------------------------------------------------------------
__global__ __launch_bounds__(256) void k_gate_combine(
    const __bf16* __restrict__ zxb, const unsigned short* __restrict__ y,
    const float* __restrict__ nw_f, const float* __restrict__ nw_r,
    const int* __restrict__ lengths, unsigned short* __restrict__ comb) {
  const int bx = blockIdx.x;            // b*SEQ + l
  const int b = bx >> 10, l = bx & 1023;
  const int tid = threadIdx.x;
  const int len = lengths[b];
  const int pos = (l < len) ? (len - 1 - l) : l;
  const int c0 = tid * 8;
  const __bf16* z = zxb + (size_t)bx * DPROJ_PAD;
  const __bf16* yf = (const __bf16*)(y + ((size_t)b * SEQ + l) * DINNER);
  const __bf16* yr = (const __bf16*)(y + ((size_t)(BSZ + b) * SEQ + pos) * DINNER);

  bf16x8 zv = *(const bf16x8*)(z + c0);
  bf16x8 yfv = *(const bf16x8*)(yf + c0);
  bf16x8 yrv = *(const bf16x8*)(yr + c0);
  float4 n0 = *(const float4*)(nw_f + c0);
  float4 n1 = *(const float4*)(nw_f + c0 + 4);
  float4 m0 = *(const float4*)(nw_r + c0);
  float4 m1 = *(const float4*)(nw_r + c0 + 4);

  float gf[8], gr[8];
  float sf = 0.f, sr = 0.f;
#pragma unroll
  for (int k = 0; k < 8; ++k) {
    float zz = (float)zv[k];
    float sz = zz / (1.f + __expf(-zz));
    float vf = (float)yfv[k] * sz;
    float vr = (float)yrv[k] * sz;
    gf[k] = vf; gr[k] = vr;
    sf += vf * vf; sr += vr * vr;
  }
  for (int o = 32; o > 0; o >>= 1) { sf += __shfl_down(sf, o); sr += __shfl_down(sr, o); }
  __shared__ float red[8];
  if ((tid & 63) == 0) { red[tid >> 6] = sf; red[4 + (tid >> 6)] = sr; }
  __syncthreads();
  sf = red[0] + red[1] + red[2] + red[3];
  sr = red[4] + red[5] + red[6] + red[7];
  float rf = rsqrtf(sf * (1.f / DINNER) + EPSF);
  float rr = rsqrtf(sr * (1.f / DINNER) + EPSF);
  const float nwf[8] = {n0.x, n0.y, n0.z, n0.w, n1.x, n1.y, n1.z, n1.w};
  const float nwr[8] = {m0.x, m0.y, m0.z, m0.w, m1.x, m1.y, m1.z, m1.w};
  bf16x8 ov;
#pragma unroll
  for (int k = 0; k < 8; ++k) {
    float o = 0.5f * (gf[k] * rf * nwf[k] + gr[k] * rr * nwr[k]);
    ov[k] = (__bf16)o;
  }
  *(bf16x8*)((__bf16*)comb + (size_t)bx * DINNER + c0) = ov;
}

// ---------------------------------------------------------------------------
extern "C" void kernel_launch(void* const* d_in, const int* in_sizes, int n_in,
                              void* d_out, int out_size, void* d_ws, size_t ws_size,
                              hipStream_t stream) {
  const float* hidden      = (const float*)d_in[0];
  const unsigned char* msk = (const unsigned char*)d_in[1];
  const float* in_proj_w   = (const float*)d_in[2];
  const float* out_proj_w  = (const float*)d_in[3];
  const float* conv_w_f    = (const float*)d_in[4];
  const float* conv_b_f    = (const float*)d_in[5];
  const float* dt_bias_f   = (const float*)d_in[6];
  const float* A_log_f     = (const float*)d_in[7];
  const float* D_f         = (const float*)d_in[8];
  const float* norm_w_f    = (const float*)d_in[9];
  const float* conv_w_r    = (const float*)d_in[10];
  const float* conv_b_r    = (const float*)d_in[11];
  const float* dt_bias_r   = (const float*)d_in[12];
  const float* A_log_r     = (const float*)d_in[13];
  const float* D_r         = (const float*)d_in[14];
  const float* norm_w_r    = (const float*)d_in[15];
  float* outF = (float*)d_out;

  char* ws = (char*)d_ws;
  size_t o_w1b  = 0;                         // bf16 [4480][1024]
  size_t o_w2b  = o_w1b  + 9175040;          // bf16 [1024][2048]
  size_t o_hb   = o_w2b  + 4194304;          // bf16 [4096][1024]
  size_t o_zx   = o_hb   + 8388608;          // bf16 [4096][4480]
  size_t o_xb   = o_zx   + 36700160;         // bf16 [2][4096][2304]
  size_t o_dd   = o_xb   + 37748736;         // f32  [8192][128]
  size_t o_y    = o_dd   + 4194304;          // bf16 [2][4096][2048]
  size_t o_comb = o_y    + 33554432;         // bf16 [4096][2048]
  size_t o_outp = o_comb + 16777216;         // bf16 [4096][1024]
  size_t o_len  = o_outp + 8388608;          // int  [4]

  unsigned short* W1b  = (unsigned short*)(ws + o_w1b);
  unsigned short* W2b  = (unsigned short*)(ws + o_w2b);
  unsigned short* hb   = (unsigned short*)(ws + o_hb);
  __bf16*         zxb  = (__bf16*)(ws + o_zx);
  __bf16*         xb   = (__bf16*)(ws + o_xb);
  float*          ddg  = (float*)(ws + o_dd);
  unsigned short* yB   = (unsigned short*)(ws + o_y);
  unsigned short* comb = (unsigned short*)(ws + o_comb);
  unsigned short* outp = (unsigned short*)(ws + o_outp);
  int*            lens = (int*)(ws + o_len);

  k_prep<<<CONV_BLKS + NTOK + BSZ, 256, 0, stream>>>(
      hidden, msk, in_proj_w, out_proj_w, W1b, W2b, hb, lens);

  k_gemm_bt_h<<<dim3(NTOK / 128, DPROJ_PAD / 128), 256, 0, stream>>>(
      hb, W1b, (unsigned short*)zxb, DMODEL, DMODEL, DMODEL, DPROJ_PAD);

  k_conv<<<2 * BSZ * (SEQ / 16), 256, 0, stream>>>(
      zxb, conv_w_f, conv_b_f, conv_w_r, conv_b_r, lens, xb);

  k_dtprep<<<1024, 256, 0, stream>>>(
      zxb, dt_bias_f, dt_bias_r, A_log_f, A_log_r, lens, ddg);

  k_scan<<<2 * BSZ * NHEADS, 256, 0, stream>>>(xb, ddg, D_f, D_r, yB);

  k_gate_combine<<<NTOK, 256, 0, stream>>>(zxb, yB, norm_w_f, norm_w_r, lens, comb);

  k_gemm_bt_h<<<dim3(NTOK / 128, DMODEL / 128), 256, 0, stream>>>(
      comb, W2b, outp, DINNER, DINNER, DINNER, DMODEL);

  k_ln_out<<<NTOK, 256, 0, stream>>>(outp, outF);

  (void)in_sizes; (void)n_in; (void)out_size; (void)ws_size;
}

// Round 9
// 284.933 us; speedup vs baseline: 1.1745x; 1.0663x over previous
//
#include <hip/hip_runtime.h>

// ---------------------------------------------------------------------------
// BiMamba2 (D_MODEL=1024, D_INNER=2048, NHEADS=32, HEADDIM=64, D_STATE=128,
// D_CONV=4, B=4, L=1024).  Pipeline (7 dispatches):
//   prep(convert x8-vec + ln1 + lengths) -> GEMM1 (128x128) ->
//   convdt(conv + dtprep fused) -> chunked MFMA scan (R7, frozen) ->
//   gate+RMS+combine -> GEMM2 (64x128, 2 blocks/CU) -> ln2
//
// R16 (on top of R15's 303.8us):
//   - GEMM2 moved to a BM=64 variant: grid 256 -> 512 blocks = 2 independent
//     blocks/CU (was 1 -> zero overlap of the per-K-step barrier drains).
//     Same per-output K/MFMA order -> bit-identical.
//   - weight conversion vectorized x8 (two float4 -> u16x8; same f2bf).
//   - k_conv + k_dtprep fused (block-uniform branch; both read zxb).
// k_scan frozen at R7 (60.3us; R8-R14 established every perturbation is a
// regression).
// ---------------------------------------------------------------------------

#define BSZ 4
#define SEQ 1024
#define DMODEL 1024
#define DINNER 2048
#define NHEADS 32
#define HEADDIM 64
#define DSTATE 128
#define CONVDIM 2304            // DINNER + 2*DSTATE
#define DPROJ 4384              // 2*DINNER + 2*DSTATE + NHEADS
#define DPROJ_PAD 4480          // padded to multiple of 128
#define NTOK (BSZ*SEQ)          // 4096
#define EPSF 1e-5f
#define CH 32                   // scan chunk length
#define NCHK (SEQ/CH)           // 32 chunks

typedef float f32x4 __attribute__((ext_vector_type(4)));
typedef __bf16 bf16x8 __attribute__((ext_vector_type(8)));
typedef unsigned short u16x8 __attribute__((ext_vector_type(8)));

__device__ __forceinline__ unsigned short f2bf(float f) {
  unsigned int x = __float_as_uint(f);
  unsigned int r = (x + 0x7fffu + ((x >> 16) & 1u)) >> 16;
  return (unsigned short)r;
}
__device__ __forceinline__ float bf2f(unsigned short u) {
  return __uint_as_float(((unsigned int)u) << 16);
}

__device__ __forceinline__ void async_load16(const void* g, void* l) {
  __builtin_amdgcn_global_load_lds(
      (const __attribute__((address_space(1))) void*)g,
      (__attribute__((address_space(3))) void*)l, 16, 0, 0);
}

// ---------------------------------------------------------------------------
// Merged prep: weight conversion (x8-vectorized) + LayerNorm1 + lengths.
// ---------------------------------------------------------------------------
#define W1N (DPROJ_PAD * DMODEL)          // 4587520 (divisible by 8)
#define W2N (DMODEL * DINNER)             // 2097152
#define CONV_BLKS ((W1N + W2N) / 2048)    // 3264 blocks, 8 elems/thread

__global__ __launch_bounds__(256) void k_prep(
    const float* __restrict__ hidden, const unsigned char* __restrict__ msk,
    const float* __restrict__ w1, const float* __restrict__ w2,
    unsigned short* __restrict__ o1, unsigned short* __restrict__ o2,
    unsigned short* __restrict__ hb, int* __restrict__ lengths) {
  const int bid = blockIdx.x;
  const int tid = threadIdx.x;
  __shared__ float redf[8];
  __shared__ int redi[4];

  if (bid < CONV_BLKS) {
    // ---- weight conversion, 8 consecutive elems per thread ----
    int idx = (bid * 256 + tid) * 8;
    if (idx < W1N) {
      int row = idx >> 10, col = idx & 1023;
      u16x8 o;
      if (row < DPROJ) {
        const float* wr = w1 + (size_t)row * DMODEL + col;
#pragma unroll
        for (int j = 0; j < 8; ++j) o[j] = f2bf(wr[j]);
      } else {
#pragma unroll
        for (int j = 0; j < 8; ++j) o[j] = 0;
      }
      *(u16x8*)(o1 + idx) = o;
    } else {
      int k = idx - W1N;
      const float* wr = w2 + k;
      u16x8 o;
#pragma unroll
      for (int j = 0; j < 8; ++j) o[j] = f2bf(wr[j]);
      *(u16x8*)(o2 + k) = o;
    }
  } else if (bid < CONV_BLKS + NTOK) {
    // ---- LayerNorm (1024 wide, fp32 in) -> bf16 ----
    int row = bid - CONV_BLKS;
    float4 v = ((const float4*)(hidden + (size_t)row * DMODEL))[tid];
    float s = v.x + v.y + v.z + v.w;
    float ss = v.x * v.x + v.y * v.y + v.z * v.z + v.w * v.w;
    for (int o = 32; o > 0; o >>= 1) { s += __shfl_down(s, o); ss += __shfl_down(ss, o); }
    if ((tid & 63) == 0) { redf[tid >> 6] = s; redf[4 + (tid >> 6)] = ss; }
    __syncthreads();
    s = redf[0] + redf[1] + redf[2] + redf[3];
    ss = redf[4] + redf[5] + redf[6] + redf[7];
    float mu = s * (1.f / DMODEL);
    float var = ss * (1.f / DMODEL) - mu * mu;
    float rs = rsqrtf(var + EPSF);
    ushort4 o;
    o.x = f2bf((v.x - mu) * rs); o.y = f2bf((v.y - mu) * rs);
    o.z = f2bf((v.z - mu) * rs); o.w = f2bf((v.w - mu) * rs);
    ((ushort4*)(hb + (size_t)row * DMODEL))[tid] = o;
  } else {
    // ---- lengths ----
    int b = bid - CONV_BLKS - NTOK;
    int cnt = 0;
    for (int k = 0; k < 4; ++k)
      cnt += (msk[(size_t)b * SEQ + tid + k * 256] == 0) ? 1 : 0;
    for (int o = 32; o > 0; o >>= 1) cnt += __shfl_down(cnt, o);
    if ((tid & 63) == 0) redi[tid >> 6] = cnt;
    __syncthreads();
    if (tid == 0) lengths[b] = redi[0] + redi[1] + redi[2] + redi[3];
  }
}

// LayerNorm (1024 wide, bf16 in) -> fp32 out (final)
__global__ __launch_bounds__(256) void k_ln_out(const unsigned short* __restrict__ in,
                                                float* __restrict__ out) {
  int row = blockIdx.x, tid = threadIdx.x;
  ushort4 u = ((const ushort4*)(in + (size_t)row * DMODEL))[tid];
  float4 v;
  v.x = bf2f(u.x); v.y = bf2f(u.y); v.z = bf2f(u.z); v.w = bf2f(u.w);
  float s = v.x + v.y + v.z + v.w;
  float ss = v.x * v.x + v.y * v.y + v.z * v.z + v.w * v.w;
  for (int o = 32; o > 0; o >>= 1) { s += __shfl_down(s, o); ss += __shfl_down(ss, o); }
  __shared__ float red[8];
  if ((tid & 63) == 0) { red[tid >> 6] = s; red[4 + (tid >> 6)] = ss; }
  __syncthreads();
  s = red[0] + red[1] + red[2] + red[3];
  ss = red[4] + red[5] + red[6] + red[7];
  float mu = s * (1.f / DMODEL);
  float var = ss * (1.f / DMODEL) - mu * mu;
  float rs = rsqrtf(var + EPSF);
  float4 o;
  o.x = (v.x - mu) * rs; o.y = (v.y - mu) * rs;
  o.z = (v.z - mu) * rs; o.w = (v.w - mu) * rs;
  ((float4*)(out + (size_t)row * DMODEL))[tid] = o;
}

// ---------------------------------------------------------------------------
// bf16 MFMA GEMM (B^T form), BM=128: C[M,N] = A[M,K] * B[N,K]^T, bf16 out.
// Used for GEMM1 (grid 32x35 = 1120 blocks, ~4.4/CU).
// ---------------------------------------------------------------------------
__global__ __launch_bounds__(256) void k_gemm_bt_h(const unsigned short* __restrict__ A,
                                                   const unsigned short* __restrict__ B,
                                                   unsigned short* __restrict__ C,
                                                   int K, int lda, int ldb, int ldc) {
  __shared__ unsigned short Asm[2][128 * 32];
  __shared__ unsigned short Bsm[2][128 * 32];
  const int tid = threadIdx.x;
  const int lane = tid & 63;
  const int w = tid >> 6;
  const int wm = w >> 1, wn = w & 1;
  const long m0 = (long)blockIdx.x * 128;
  const long n0 = (long)blockIdx.y * 128;

  const int sr = lane >> 2;
  const int sc = (lane & 3) * 8;
  const unsigned short* gA0 = A + (m0 + (w * 2 + 0) * 16 + sr) * (long)lda + sc;
  const unsigned short* gA1 = A + (m0 + (w * 2 + 1) * 16 + sr) * (long)lda + sc;
  const unsigned short* gB0 = B + (n0 + (w * 2 + 0) * 16 + sr) * (long)ldb + sc;
  const unsigned short* gB1 = B + (n0 + (w * 2 + 1) * 16 + sr) * (long)ldb + sc;

  f32x4 acc[4][4] = {};
  const int q8 = (lane >> 4) * 8;
  const int r16 = lane & 15;

  for (int k0 = 0; k0 < K; k0 += 64) {
#pragma unroll
    for (int h = 0; h < 2; ++h) {
      const int ko = k0 + h * 32;
      async_load16(gA0 + ko, Asm[h] + (w * 2 + 0) * 512);
      async_load16(gA1 + ko, Asm[h] + (w * 2 + 1) * 512);
      async_load16(gB0 + ko, Bsm[h] + (w * 2 + 0) * 512);
      async_load16(gB1 + ko, Bsm[h] + (w * 2 + 1) * 512);
    }
    __syncthreads();
#pragma unroll
    for (int h = 0; h < 2; ++h) {
      bf16x8 af[4], bfr[4];
#pragma unroll
      for (int i = 0; i < 4; ++i)
        af[i] = *reinterpret_cast<const bf16x8*>(Asm[h] + (wm * 64 + i * 16 + r16) * 32 + q8);
#pragma unroll
      for (int j = 0; j < 4; ++j)
        bfr[j] = *reinterpret_cast<const bf16x8*>(Bsm[h] + (wn * 64 + j * 16 + r16) * 32 + q8);
#pragma unroll
      for (int i = 0; i < 4; ++i)
#pragma unroll
        for (int j = 0; j < 4; ++j)
          acc[i][j] = __builtin_amdgcn_mfma_f32_16x16x32_bf16(af[i], bfr[j], acc[i][j], 0, 0, 0);
    }
    __syncthreads();
  }
  const int q = lane >> 4, cn = lane & 15;
#pragma unroll
  for (int i = 0; i < 4; ++i)
#pragma unroll
    for (int j = 0; j < 4; ++j) {
      long crow = m0 + wm * 64 + i * 16 + q * 4;
      long ccol = n0 + wn * 64 + j * 16 + cn;
#pragma unroll
      for (int r = 0; r < 4; ++r)
        C[(crow + r) * (long)ldc + ccol] = f2bf(acc[i][j][r]);
    }
}

// ---------------------------------------------------------------------------
// bf16 MFMA GEMM, BM=64 variant (R16).  Used for GEMM2: grid (M/64, N/128) =
// (64, 8) = 512 blocks -> 2 independent blocks/CU (vs 1 at BM=128), LDS 24KB.
// Per-output K-iteration and MFMA order identical to the BM=128 kernel ->
// bit-identical results.
// ---------------------------------------------------------------------------
__global__ __launch_bounds__(256) void k_gemm_bt_h64(const unsigned short* __restrict__ A,
                                                     const unsigned short* __restrict__ B,
                                                     unsigned short* __restrict__ C,
                                                     int K, int lda, int ldb, int ldc) {
  __shared__ unsigned short Asm[2][64 * 32];     // 8 KB
  __shared__ unsigned short Bsm[2][128 * 32];    // 16 KB
  const int tid = threadIdx.x;
  const int lane = tid & 63;
  const int w = tid >> 6;
  const int wm = w >> 1, wn = w & 1;             // wm: 32-row band, wn: 64-col band
  const long m0 = (long)blockIdx.x * 64;
  const long n0 = (long)blockIdx.y * 128;

  const int sr = lane >> 2;
  const int sc = (lane & 3) * 8;
  const unsigned short* gA  = A + (m0 + w * 16 + sr) * (long)lda + sc;          // tile w
  const unsigned short* gB0 = B + (n0 + (w * 2 + 0) * 16 + sr) * (long)ldb + sc;
  const unsigned short* gB1 = B + (n0 + (w * 2 + 1) * 16 + sr) * (long)ldb + sc;

  f32x4 acc[2][4] = {};
  const int q8 = (lane >> 4) * 8;
  const int r16 = lane & 15;

  for (int k0 = 0; k0 < K; k0 += 64) {
#pragma unroll
    for (int h = 0; h < 2; ++h) {
      const int ko = k0 + h * 32;
      async_load16(gA + ko, Asm[h] + w * 512);
      async_load16(gB0 + ko, Bsm[h] + (w * 2 + 0) * 512);
      async_load16(gB1 + ko, Bsm[h] + (w * 2 + 1) * 512);
    }
    __syncthreads();
#pragma unroll
    for (int h = 0; h < 2; ++h) {
      bf16x8 af[2], bfr[4];
#pragma unroll
      for (int i = 0; i < 2; ++i)
        af[i] = *reinterpret_cast<const bf16x8*>(Asm[h] + (wm * 32 + i * 16 + r16) * 32 + q8);
#pragma unroll
      for (int j = 0; j < 4; ++j)
        bfr[j] = *reinterpret_cast<const bf16x8*>(Bsm[h] + (wn * 64 + j * 16 + r16) * 32 + q8);
#pragma unroll
      for (int i = 0; i < 2; ++i)
#pragma unroll
        for (int j = 0; j < 4; ++j)
          acc[i][j] = __builtin_amdgcn_mfma_f32_16x16x32_bf16(af[i], bfr[j], acc[i][j], 0, 0, 0);
    }
    __syncthreads();
  }
  const int q = lane >> 4, cn = lane & 15;
#pragma unroll
  for (int i = 0; i < 2; ++i)
#pragma unroll
    for (int j = 0; j < 4; ++j) {
      long crow = m0 + wm * 32 + i * 16 + q * 4;
      long ccol = n0 + wn * 64 + j * 16 + cn;
#pragma unroll
      for (int r = 0; r < 4; ++r)
        C[(crow + r) * (long)ldc + ccol] = f2bf(acc[i][j][r]);
    }
}

// ---------------------------------------------------------------------------
// Fused: depthwise causal conv (width 4) + SiLU (blocks 0..511) and
// dt/decay table precompute (blocks 512..1535).  Both read zxb only.
// Conv: thread owns 8 consecutive channels + 1 tail channel (R15 layout).
// dtprep: one 32-lane group per (db,h,chunk); ddg[task][128] dt/cd/W/P.
// ---------------------------------------------------------------------------
#define CONV_GRID (2 * BSZ * (SEQ / 16))   // 512

__global__ __launch_bounds__(256) void k_convdt(
    const __bf16* __restrict__ zxb,
    const float* __restrict__ cw_f, const float* __restrict__ cb_f,
    const float* __restrict__ cw_r, const float* __restrict__ cb_r,
    const float* __restrict__ dtb_f, const float* __restrict__ dtb_r,
    const float* __restrict__ al_f, const float* __restrict__ al_r,
    const int* __restrict__ lengths,
    __bf16* __restrict__ xb, float* __restrict__ ddg) {
  const int tid = threadIdx.x;

  if (blockIdx.x < CONV_GRID) {
    // ================= conv =================
    const int bx = blockIdx.x;                // db*64 + tg
    const int tg = bx & 63;
    const int db = bx >> 6;
    const int b = db & 3;
    const int dir = db >> 2;
    const int len = lengths[b];
    const int t0 = tg * 16;

    const float* cw = dir ? cw_r : cw_f;
    const float* cb = dir ? cb_r : cb_f;

    const int cA = tid * 8;          // 8 consecutive channels in [0,2048)
    const int cB = 2048 + tid;       // tail channel in [2048,2304)

    float wA0[8], wA1[8], wA2[8], wA3[8], bA[8];
    float rA0[8], rA1[8], rA2[8], rA3[8];
#pragma unroll
    for (int j = 0; j < 8; ++j) {
      float4 w4 = *(const float4*)(cw + (size_t)(cA + j) * 4);
      wA0[j] = w4.x; wA1[j] = w4.y; wA2[j] = w4.z; wA3[j] = w4.w;
      bA[j] = cb[cA + j];
      rA0[j] = 0.f; rA1[j] = 0.f; rA2[j] = 0.f;
    }
    float4 wB4 = *(const float4*)(cw + (size_t)cB * 4);
    float bB = cb[cB];
    float rB0 = 0.f, rB1 = 0.f, rB2 = 0.f, rB3;

    auto rowptr = [&](int tt) -> const __bf16* {
      int s = dir ? ((tt < len) ? (len - 1 - tt) : tt) : tt;
      return zxb + ((size_t)b * SEQ + s) * DPROJ_PAD + DINNER;
    };
    auto loadA = [&](const __bf16* rp, float* dst) {
      bf16x8 v = *(const bf16x8*)(rp + cA);
#pragma unroll
      for (int j = 0; j < 8; ++j) dst[j] = (float)v[j];
    };

    if (t0 >= 3) {
      const __bf16* ra = rowptr(t0 - 3);
      const __bf16* rb = rowptr(t0 - 2);
      const __bf16* rc = rowptr(t0 - 1);
      loadA(ra, rA0); loadA(rb, rA1); loadA(rc, rA2);
      rB0 = (float)ra[cB]; rB1 = (float)rb[cB]; rB2 = (float)rc[cB];
    }
    {
      const __bf16* rp = rowptr(t0);
      loadA(rp, rA3);
      rB3 = (float)rp[cB];
    }
    for (int j = 0; j < 16; ++j) {
      float r4A[8] = {};
      float r4B = 0.f;
      if (j < 15) {
        const __bf16* rp = rowptr(t0 + j + 1);
        loadA(rp, r4A);
        r4B = (float)rp[cB];
      }
      __bf16* orow = xb + ((size_t)db * SEQ + t0 + j) * CONVDIM;
      bf16x8 ov;
#pragma unroll
      for (int k = 0; k < 8; ++k) {
        float acc = bA[k];
        acc = fmaf(wA0[k], rA0[k], acc);
        acc = fmaf(wA1[k], rA1[k], acc);
        acc = fmaf(wA2[k], rA2[k], acc);
        acc = fmaf(wA3[k], rA3[k], acc);
        float sig = 1.f / (1.f + __expf(-acc));
        ov[k] = (__bf16)(acc * sig);
        rA0[k] = rA1[k]; rA1[k] = rA2[k]; rA2[k] = rA3[k]; rA3[k] = r4A[k];
      }
      *(bf16x8*)(orow + cA) = ov;
      {
        float acc = bB;
        acc = fmaf(wB4.x, rB0, acc);
        acc = fmaf(wB4.y, rB1, acc);
        acc = fmaf(wB4.z, rB2, acc);
        acc = fmaf(wB4.w, rB3, acc);
        float sig = 1.f / (1.f + __expf(-acc));
        orow[cB] = (__bf16)(acc * sig);
        rB0 = rB1; rB1 = rB2; rB2 = rB3; rB3 = r4B;
      }
    }
  } else {
    // ================= dtprep =================
    const int task = ((blockIdx.x - CONV_GRID) * 256 + tid) >> 5;  // (db*32+h)*32+chunk
    const int l32 = tid & 31;
    const int chunk = task & 31, hh = (task >> 5) & 31, db = task >> 10;
    const int b = db & 3, dir = db >> 2;
    const int len = lengths[b];
    const float dtbv = (dir ? dtb_r : dtb_f)[hh];
    const float Ah = -__expf((dir ? al_r : al_f)[hh]);
    const int s = chunk * 32 + l32;
    const int sf = dir ? ((s < len) ? (len - 1 - s) : s) : s;
    float raw = (float)zxb[(size_t)(b * SEQ + sf) * DPROJ_PAD + DINNER + CONVDIM + hh] + dtbv;
    float d = (raw > 20.f) ? raw : log1pf(__expf(raw));
    float cum = d;
#pragma unroll
    for (int o = 1; o < 32; o <<= 1) {
      float v = __shfl_up(cum, o, 32);
      if (l32 >= o) cum += v;
    }
    float cum31 = __shfl(cum, 31, 32);
    float* o = ddg + (size_t)task * 128;
    o[l32]      = d;
    o[32 + l32] = Ah * cum;
    o[64 + l32] = d * __expf(Ah * (cum31 - cum));
    o[96 + l32] = __expf(Ah * cum);
  }
}

// ---------------------------------------------------------------------------
// Chunked MFMA selective scan, frag-linear LDS (R7 structure, frozen).
// Single-buffered raw staging, 2 blocks/CU.
// ---------------------------------------------------------------------------
__global__ __launch_bounds__(256, 2) void k_scan(
    const __bf16* __restrict__ xb, const float* __restrict__ ddg,
    const float* __restrict__ D_f, const float* __restrict__ D_r,
    unsigned short* __restrict__ y) {
  __shared__ __bf16 Crawf[4096];      // C frag-linear, 8 tiles (tt,kk)
  __shared__ __bf16 Brawf[4096];      // B frag-linear (B-as-rows x k=n)
  __shared__ __bf16 Braw2[4096];      // B row-major [s][n] (for BT repack)
  __shared__ __bf16 BTf[4096];        // B^T frag-linear, 8 tiles (ng)
  __shared__ float  ddL[2][128];      // dt/cd/W/P tables (double)
  __shared__ __bf16 SL[1024];         // S frag-linear, 2 tiles (t-halves)
  __shared__ __bf16 HL[4][2048];      // per-wave H frag-linear, 4 tiles (kk)
  __shared__ __bf16 yO[2][32 * 72];   // y chunk [t][p], stride 72 (double)

  const int bx = blockIdx.x;          // db*32 + h
  const int h = bx & 31;
  const int db = bx >> 5;
  const int dir = db >> 2;
  const int tid = threadIdx.x;
  const int lane = tid & 63;
  const int w = tid >> 6;
  const int l15 = lane & 15;
  const int q = lane >> 4;

  const float Dh = (dir ? D_r : D_f)[h];
  const __bf16* xbase = xb + (size_t)db * SEQ * CONVDIM;
  const float* ddbase = ddg + (size_t)bx * NCHK * 128;
  unsigned short* ybase = y + (size_t)db * SEQ * DINNER + h * HEADDIM;

  for (int i = lane; i < 2048; i += 64) HL[w][i] = (__bf16)0.f;
  for (int i = tid; i < 1024; i += 256) SL[i] = (__bf16)0.f;

  f32x4 accH[8] = {};

  auto issue = [&](int c, int nb) {
    const __bf16* xr = xbase + (size_t)c * CH * CONVDIM;
#pragma unroll
    for (int k = 0; k < 2; ++k) {
      const int idx = w * 2 + k;              // 0..7
      const int P = idx * 64 + lane;
      const int tt = P >> 8, kk = (P >> 6) & 3, qq = (P >> 4) & 3, ll = P & 15;
      const __bf16* gB = xr + (size_t)(tt * 16 + ll) * CONVDIM + DINNER + kk * 32 + qq * 8;
      async_load16(gB, &Brawf[idx * 512]);
      async_load16(gB + 128, &Crawf[idx * 512]);
      const int s = P >> 4, n8 = P & 15;
      const __bf16* g2 = xr + (size_t)s * CONVDIM + DINNER + n8 * 8;
      async_load16(g2, &Braw2[idx * 512]);
    }
    if (w == 3 && lane < 32)
      async_load16(ddbase + (size_t)c * 128 + lane * 4, &ddL[nb][0]);
  };

  auto load_xt = [&](int c) {
    bf16x8 v;
    const __bf16* gx = xbase + (size_t)(c * CH + q * 8) * CONVDIM + h * HEADDIM + w * 16 + l15;
#pragma unroll
    for (int j = 0; j < 8; ++j) v[j] = gx[(size_t)j * CONVDIM];
    return v;
  };

  issue(0, 0);
  bf16x8 xt = load_xt(0);
  __syncthreads();

  for (int c = 0; c < NCHK; ++c) {
    const int cb = c & 1, nb = cb ^ 1;

    // ---------------- phase 1 (reads of raw staging buffers) ----------------
    if (c > 0) {   // flush previous chunk's y (coalesced)
      const int tf = tid >> 3, p8 = (tid & 7) * 8;
      bf16x8 vy = *(const bf16x8*)&yO[nb][tf * 72 + p8];
      *(bf16x8*)(ybase + (size_t)((c - 1) * CH + tf) * DINNER + p8) = vy;
    }

    // B^T repack from row-major Braw2
    {
      const int n = tid & 127, sg = tid >> 7;
#pragma unroll
      for (int e = 0; e < 2; ++e) {
        const int qp = sg * 2 + e;            // q' = s>>3
        bf16x8 v;
#pragma unroll
        for (int j = 0; j < 8; ++j) v[j] = Braw2[(qp * 8 + j) * 128 + n];
        *(bf16x8*)&BTf[((n >> 4) * 64 + qp * 16 + (n & 15)) * 8] = v;
      }
    }

    // C frags (all waves); G quadrant + mask (waves 0-2)
    bf16x8 Cf0[4], Cf1[4];
#pragma unroll
    for (int kk = 0; kk < 4; ++kk) {
      Cf0[kk] = *(const bf16x8*)&Crawf[(kk * 64 + lane) * 8];
      Cf1[kk] = *(const bf16x8*)&Crawf[((4 + kk) * 64 + lane) * 8];
    }
    if (w < 3) {
      const int tt = (w == 0) ? 0 : 1;
      const int ss = (w == 2) ? 1 : 0;
      f32x4 G = {};
#pragma unroll
      for (int kk = 0; kk < 4; ++kk) {
        bf16x8 Bq = *(const bf16x8*)&Brawf[((ss * 4 + kk) * 64 + lane) * 8];
        G = __builtin_amdgcn_mfma_f32_16x16x32_bf16(tt ? Cf1[kk] : Cf0[kk], Bq, G, 0, 0, 0);
      }
      const int sgl = ss * 16 + l15;
      const float sdt = ddL[cb][sgl];
      const float scd = ddL[cb][32 + sgl];
#pragma unroll
      for (int r = 0; r < 4; ++r) {
        const int t0 = q * 4 + r;
        float v = G[r] * sdt * __expf(ddL[cb][32 + tt * 16 + t0] - scd);
        if (tt == ss) {
          if (t0 < l15) v = 0.f;
          else if (t0 == l15) v += Dh;         // absorb D*x into S diagonal
        }
        SL[(tt * 64 + (ss * 2 + (l15 >> 3)) * 16 + t0) * 8 + (l15 & 7)] = (__bf16)v;
      }
    }
    __syncthreads();   // barrier A — raw-buffer reads complete block-wide

    // ---------------- phase 2 ----------------
    if (c + 1 < NCHK) issue(c + 1, nb);       // safe: single-buffer overwrite
    bf16x8 xt_n;
    if (c + 1 < NCHK) xt_n = load_xt(c + 1);

    // y_intra: y^T[p][t] = X^T @ S^T
    f32x4 accy0 = {}, accy1 = {};
    {
      bf16x8 S0 = *(const bf16x8*)&SL[(lane) * 8];
      bf16x8 S1 = *(const bf16x8*)&SL[(64 + lane) * 8];
      accy0 = __builtin_amdgcn_mfma_f32_16x16x32_bf16(xt, S0, accy0, 0, 0, 0);
      accy1 = __builtin_amdgcn_mfma_f32_16x16x32_bf16(xt, S1, accy1, 0, 0, 0);
    }
    // y_inter: (H_prev @ C^T) .* P_t
    {
      f32x4 ai0 = {}, ai1 = {};
#pragma unroll
      for (int kk = 0; kk < 4; ++kk) {
        bf16x8 Hf = *(const bf16x8*)&HL[w][(kk * 64 + lane) * 8];
        ai0 = __builtin_amdgcn_mfma_f32_16x16x32_bf16(Hf, Cf0[kk], ai0, 0, 0, 0);
        ai1 = __builtin_amdgcn_mfma_f32_16x16x32_bf16(Hf, Cf1[kk], ai1, 0, 0, 0);
      }
      const float P0 = ddL[cb][96 + l15], P1 = ddL[cb][96 + 16 + l15];
      accy0 = accy0 + ai0 * P0;
      accy1 = accy1 + ai1 * P1;
    }
    // H update: H = atot*H + (X.*W)^T @ B
    {
      const float atot = ddL[cb][96 + 31];
      bf16x8 xw;
#pragma unroll
      for (int j = 0; j < 8; ++j)
        xw[j] = (__bf16)((float)xt[j] * ddL[cb][64 + q * 8 + j]);
#pragma unroll
      for (int nt = 0; nt < 8; ++nt) {
        bf16x8 Bt = *(const bf16x8*)&BTf[(nt * 64 + lane) * 8];
        accH[nt] = accH[nt] * atot;
        accH[nt] = __builtin_amdgcn_mfma_f32_16x16x32_bf16(xw, Bt, accH[nt], 0, 0, 0);
      }
#pragma unroll
      for (int nt = 0; nt < 8; ++nt)
#pragma unroll
        for (int r = 0; r < 4; ++r) {
          const int n = nt * 16 + l15;
          HL[w][((n >> 5) * 64 + ((n & 31) >> 3) * 16 + q * 4 + r) * 8 + (n & 7)] =
              (__bf16)accH[nt][r];
        }
    }
    // stage y chunk
#pragma unroll
    for (int r = 0; r < 4; ++r) {
      const int p = w * 16 + q * 4 + r;
      yO[cb][l15 * 72 + p]        = (__bf16)accy0[r];
      yO[cb][(16 + l15) * 72 + p] = (__bf16)accy1[r];
    }
    xt = xt_n;
    __syncthreads();   // barrier B (drains async staging for c+1)
  }
  {  // final flush
    const int tf = tid >> 3, p8 = (tid & 7) * 8;
    bf16x8 vy = *(const bf16x8*)&yO[(NCHK - 1) & 1][tf * 72 + p8];
    *(bf16x8*)(ybase + (size_t)((NCHK - 1) * CH + tf) * DINNER + p8) = vy;
  }
}

// ---------------------------------------------------------------------------
// Gate (y * silu(z)) + RMSNorm per direction + average-with-flip -> bf16.
// ---------------------------------------------------------------------------
__global__ __launch_bounds__(256) void k_gate_combine(
    const __bf16* __restrict__ zxb, const unsigned short* __restrict__ y,
    const float* __restrict__ nw_f, const float* __restrict__ nw_r,
    const int* __restrict__ lengths, unsigned short* __restrict__ comb) {
  const int bx = blockIdx.x;            // b*SEQ + l
  const int b = bx >> 10, l = bx & 1023;
  const int tid = threadIdx.x;
  const int len = lengths[b];
  const int pos = (l < len) ? (len - 1 - l) : l;
  const int c0 = tid * 8;
  const __bf16* z = zxb + (size_t)bx * DPROJ_PAD;
  const __bf16* yf = (const __bf16*)(y + ((size_t)b * SEQ + l) * DINNER);
  const __bf16* yr = (const __bf16*)(y + ((size_t)(BSZ + b) * SEQ + pos) * DINNER);

  bf16x8 zv = *(const bf16x8*)(z + c0);
  bf16x8 yfv = *(const bf16x8*)(yf + c0);
  bf16x8 yrv = *(const bf16x8*)(yr + c0);
  float4 n0 = *(const float4*)(nw_f + c0);
  float4 n1 = *(const float4*)(nw_f + c0 + 4);
  float4 m0 = *(const float4*)(nw_r + c0);
  float4 m1 = *(const float4*)(nw_r + c0 + 4);

  float gf[8], gr[8];
  float sf = 0.f, sr = 0.f;
#pragma unroll
  for (int k = 0; k < 8; ++k) {
    float zz = (float)zv[k];
    float sz = zz / (1.f + __expf(-zz));
    float vf = (float)yfv[k] * sz;
    float vr = (float)yrv[k] * sz;
    gf[k] = vf; gr[k] = vr;
    sf += vf * vf; sr += vr * vr;
  }
  for (int o = 32; o > 0; o >>= 1) { sf += __shfl_down(sf, o); sr += __shfl_down(sr, o); }
  __shared__ float red[8];
  if ((tid & 63) == 0) { red[tid >> 6] = sf; red[4 + (tid >> 6)] = sr; }
  __syncthreads();
  sf = red[0] + red[1] + red[2] + red[3];
  sr = red[4] + red[5] + red[6] + red[7];
  float rf = rsqrtf(sf * (1.f / DINNER) + EPSF);
  float rr = rsqrtf(sr * (1.f / DINNER) + EPSF);
  const float nwf[8] = {n0.x, n0.y, n0.z, n0.w, n1.x, n1.y, n1.z, n1.w};
  const float nwr[8] = {m0.x, m0.y, m0.z, m0.w, m1.x, m1.y, m1.z, m1.w};
  bf16x8 ov;
#pragma unroll
  for (int k = 0; k < 8; ++k) {
    float o = 0.5f * (gf[k] * rf * nwf[k] + gr[k] * rr * nwr[k]);
    ov[k] = (__bf16)o;
  }
  *(bf16x8*)((__bf16*)comb + (size_t)bx * DINNER + c0) = ov;
}

// ---------------------------------------------------------------------------
extern "C" void kernel_launch(void* const* d_in, const int* in_sizes, int n_in,
                              void* d_out, int out_size, void* d_ws, size_t ws_size,
                              hipStream_t stream) {
  const float* hidden      = (const float*)d_in[0];
  const unsigned char* msk = (const unsigned char*)d_in[1];
  const float* in_proj_w   = (const float*)d_in[2];
  const float* out_proj_w  = (const float*)d_in[3];
  const float* conv_w_f    = (const float*)d_in[4];
  const float* conv_b_f    = (const float*)d_in[5];
  const float* dt_bias_f   = (const float*)d_in[6];
  const float* A_log_f     = (const float*)d_in[7];
  const float* D_f         = (const float*)d_in[8];
  const float* norm_w_f    = (const float*)d_in[9];
  const float* conv_w_r    = (const float*)d_in[10];
  const float* conv_b_r    = (const float*)d_in[11];
  const float* dt_bias_r   = (const float*)d_in[12];
  const float* A_log_r     = (const float*)d_in[13];
  const float* D_r         = (const float*)d_in[14];
  const float* norm_w_r    = (const float*)d_in[15];
  float* outF = (float*)d_out;

  char* ws = (char*)d_ws;
  size_t o_w1b  = 0;                         // bf16 [4480][1024]
  size_t o_w2b  = o_w1b  + 9175040;          // bf16 [1024][2048]
  size_t o_hb   = o_w2b  + 4194304;          // bf16 [4096][1024]
  size_t o_zx   = o_hb   + 8388608;          // bf16 [4096][4480]
  size_t o_xb   = o_zx   + 36700160;         // bf16 [2][4096][2304]
  size_t o_dd   = o_xb   + 37748736;         // f32  [8192][128]
  size_t o_y    = o_dd   + 4194304;          // bf16 [2][4096][2048]
  size_t o_comb = o_y    + 33554432;         // bf16 [4096][2048]
  size_t o_outp = o_comb + 16777216;         // bf16 [4096][1024]
  size_t o_len  = o_outp + 8388608;          // int  [4]

  unsigned short* W1b  = (unsigned short*)(ws + o_w1b);
  unsigned short* W2b  = (unsigned short*)(ws + o_w2b);
  unsigned short* hb   = (unsigned short*)(ws + o_hb);
  __bf16*         zxb  = (__bf16*)(ws + o_zx);
  __bf16*         xb   = (__bf16*)(ws + o_xb);
  float*          ddg  = (float*)(ws + o_dd);
  unsigned short* yB   = (unsigned short*)(ws + o_y);
  unsigned short* comb = (unsigned short*)(ws + o_comb);
  unsigned short* outp = (unsigned short*)(ws + o_outp);
  int*            lens = (int*)(ws + o_len);

  k_prep<<<CONV_BLKS + NTOK + BSZ, 256, 0, stream>>>(
      hidden, msk, in_proj_w, out_proj_w, W1b, W2b, hb, lens);

  k_gemm_bt_h<<<dim3(NTOK / 128, DPROJ_PAD / 128), 256, 0, stream>>>(
      hb, W1b, (unsigned short*)zxb, DMODEL, DMODEL, DMODEL, DPROJ_PAD);

  k_convdt<<<CONV_GRID + 1024, 256, 0, stream>>>(
      zxb, conv_w_f, conv_b_f, conv_w_r, conv_b_r,
      dt_bias_f, dt_bias_r, A_log_f, A_log_r, lens, xb, ddg);

  k_scan<<<2 * BSZ * NHEADS, 256, 0, stream>>>(xb, ddg, D_f, D_r, yB);

  k_gate_combine<<<NTOK, 256, 0, stream>>>(zxb, yB, norm_w_f, norm_w_r, lens, comb);

  k_gemm_bt_h64<<<dim3(NTOK / 64, DMODEL / 128), 256, 0, stream>>>(
      comb, W2b, outp, DINNER, DINNER, DINNER, DMODEL);

  k_ln_out<<<NTOK, 256, 0, stream>>>(outp, outF);

  (void)in_sizes; (void)n_in; (void)out_size; (void)ws_size;
}

// Round 10
// 284.271 us; speedup vs baseline: 1.1773x; 1.0023x over previous
//
#include <hip/hip_runtime.h>

// ---------------------------------------------------------------------------
// BiMamba2 (D_MODEL=1024, D_INNER=2048, NHEADS=32, HEADDIM=64, D_STATE=128,
// D_CONV=4, B=4, L=1024).  Pipeline (7 dispatches):
//   prep(convert x8-vec + ln1 + lengths) -> GEMM1 (BM=64, ~5 blk/CU) ->
//   convdt(conv 8t-tiled + dtprep fused) -> chunked MFMA scan (R7, frozen) ->
//   gate+RMS+combine -> GEMM2 (BM=64) -> ln2
//
// R17 (on top of R16's 284.9us):
//   - GEMM1 moved to the BM=64 kernel (R16-verified for GEMM2): 1120 -> 2240
//     blocks, ~3 -> ~5 blocks/CU co-resident.  Same K/MFMA order ->
//     bit-identical.  Extra B-panel reads are L3-resident (W1b = 9.2 MB).
//   - conv tile 16 -> 8 timesteps (512 -> 1024 blocks, 2 -> 4 blocks/CU):
//     halves the exposed latency of the serial row-load chain.  Same
//     per-output FLOP order -> bit-identical.
// k_scan frozen at R7 (60.3us; R8-R14 established every perturbation there
// is a regression).
// ---------------------------------------------------------------------------

#define BSZ 4
#define SEQ 1024
#define DMODEL 1024
#define DINNER 2048
#define NHEADS 32
#define HEADDIM 64
#define DSTATE 128
#define CONVDIM 2304            // DINNER + 2*DSTATE
#define DPROJ 4384              // 2*DINNER + 2*DSTATE + NHEADS
#define DPROJ_PAD 4480          // padded to multiple of 128
#define NTOK (BSZ*SEQ)          // 4096
#define EPSF 1e-5f
#define CH 32                   // scan chunk length
#define NCHK (SEQ/CH)           // 32 chunks

typedef float f32x4 __attribute__((ext_vector_type(4)));
typedef __bf16 bf16x8 __attribute__((ext_vector_type(8)));
typedef unsigned short u16x8 __attribute__((ext_vector_type(8)));

__device__ __forceinline__ unsigned short f2bf(float f) {
  unsigned int x = __float_as_uint(f);
  unsigned int r = (x + 0x7fffu + ((x >> 16) & 1u)) >> 16;
  return (unsigned short)r;
}
__device__ __forceinline__ float bf2f(unsigned short u) {
  return __uint_as_float(((unsigned int)u) << 16);
}

__device__ __forceinline__ void async_load16(const void* g, void* l) {
  __builtin_amdgcn_global_load_lds(
      (const __attribute__((address_space(1))) void*)g,
      (__attribute__((address_space(3))) void*)l, 16, 0, 0);
}

// ---------------------------------------------------------------------------
// Merged prep: weight conversion (x8-vectorized) + LayerNorm1 + lengths.
// ---------------------------------------------------------------------------
#define W1N (DPROJ_PAD * DMODEL)          // 4587520 (divisible by 8)
#define W2N (DMODEL * DINNER)             // 2097152
#define CONV_BLKS ((W1N + W2N) / 2048)    // 3264 blocks, 8 elems/thread

__global__ __launch_bounds__(256) void k_prep(
    const float* __restrict__ hidden, const unsigned char* __restrict__ msk,
    const float* __restrict__ w1, const float* __restrict__ w2,
    unsigned short* __restrict__ o1, unsigned short* __restrict__ o2,
    unsigned short* __restrict__ hb, int* __restrict__ lengths) {
  const int bid = blockIdx.x;
  const int tid = threadIdx.x;
  __shared__ float redf[8];
  __shared__ int redi[4];

  if (bid < CONV_BLKS) {
    // ---- weight conversion, 8 consecutive elems per thread ----
    int idx = (bid * 256 + tid) * 8;
    if (idx < W1N) {
      int row = idx >> 10, col = idx & 1023;
      u16x8 o;
      if (row < DPROJ) {
        const float* wr = w1 + (size_t)row * DMODEL + col;
#pragma unroll
        for (int j = 0; j < 8; ++j) o[j] = f2bf(wr[j]);
      } else {
#pragma unroll
        for (int j = 0; j < 8; ++j) o[j] = 0;
      }
      *(u16x8*)(o1 + idx) = o;
    } else {
      int k = idx - W1N;
      const float* wr = w2 + k;
      u16x8 o;
#pragma unroll
      for (int j = 0; j < 8; ++j) o[j] = f2bf(wr[j]);
      *(u16x8*)(o2 + k) = o;
    }
  } else if (bid < CONV_BLKS + NTOK) {
    // ---- LayerNorm (1024 wide, fp32 in) -> bf16 ----
    int row = bid - CONV_BLKS;
    float4 v = ((const float4*)(hidden + (size_t)row * DMODEL))[tid];
    float s = v.x + v.y + v.z + v.w;
    float ss = v.x * v.x + v.y * v.y + v.z * v.z + v.w * v.w;
    for (int o = 32; o > 0; o >>= 1) { s += __shfl_down(s, o); ss += __shfl_down(ss, o); }
    if ((tid & 63) == 0) { redf[tid >> 6] = s; redf[4 + (tid >> 6)] = ss; }
    __syncthreads();
    s = redf[0] + redf[1] + redf[2] + redf[3];
    ss = redf[4] + redf[5] + redf[6] + redf[7];
    float mu = s * (1.f / DMODEL);
    float var = ss * (1.f / DMODEL) - mu * mu;
    float rs = rsqrtf(var + EPSF);
    ushort4 o;
    o.x = f2bf((v.x - mu) * rs); o.y = f2bf((v.y - mu) * rs);
    o.z = f2bf((v.z - mu) * rs); o.w = f2bf((v.w - mu) * rs);
    ((ushort4*)(hb + (size_t)row * DMODEL))[tid] = o;
  } else {
    // ---- lengths ----
    int b = bid - CONV_BLKS - NTOK;
    int cnt = 0;
    for (int k = 0; k < 4; ++k)
      cnt += (msk[(size_t)b * SEQ + tid + k * 256] == 0) ? 1 : 0;
    for (int o = 32; o > 0; o >>= 1) cnt += __shfl_down(cnt, o);
    if ((tid & 63) == 0) redi[tid >> 6] = cnt;
    __syncthreads();
    if (tid == 0) lengths[b] = redi[0] + redi[1] + redi[2] + redi[3];
  }
}

// LayerNorm (1024 wide, bf16 in) -> fp32 out (final)
__global__ __launch_bounds__(256) void k_ln_out(const unsigned short* __restrict__ in,
                                                float* __restrict__ out) {
  int row = blockIdx.x, tid = threadIdx.x;
  ushort4 u = ((const ushort4*)(in + (size_t)row * DMODEL))[tid];
  float4 v;
  v.x = bf2f(u.x); v.y = bf2f(u.y); v.z = bf2f(u.z); v.w = bf2f(u.w);
  float s = v.x + v.y + v.z + v.w;
  float ss = v.x * v.x + v.y * v.y + v.z * v.z + v.w * v.w;
  for (int o = 32; o > 0; o >>= 1) { s += __shfl_down(s, o); ss += __shfl_down(ss, o); }
  __shared__ float red[8];
  if ((tid & 63) == 0) { red[tid >> 6] = s; red[4 + (tid >> 6)] = ss; }
  __syncthreads();
  s = red[0] + red[1] + red[2] + red[3];
  ss = red[4] + red[5] + red[6] + red[7];
  float mu = s * (1.f / DMODEL);
  float var = ss * (1.f / DMODEL) - mu * mu;
  float rs = rsqrtf(var + EPSF);
  float4 o;
  o.x = (v.x - mu) * rs; o.y = (v.y - mu) * rs;
  o.z = (v.z - mu) * rs; o.w = (v.w - mu) * rs;
  ((float4*)(out + (size_t)row * DMODEL))[tid] = o;
}

// ---------------------------------------------------------------------------
// bf16 MFMA GEMM, BM=64 (R16-verified): C[M,N] = A[M,K] * B[N,K]^T, bf16 out.
// Grid (M/64, N/128); LDS 24KB -> ~5 blocks/CU.  Used for GEMM1 and GEMM2.
// ---------------------------------------------------------------------------
__global__ __launch_bounds__(256) void k_gemm_bt_h64(const unsigned short* __restrict__ A,
                                                     const unsigned short* __restrict__ B,
                                                     unsigned short* __restrict__ C,
                                                     int K, int lda, int ldb, int ldc) {
  __shared__ unsigned short Asm[2][64 * 32];     // 8 KB
  __shared__ unsigned short Bsm[2][128 * 32];    // 16 KB
  const int tid = threadIdx.x;
  const int lane = tid & 63;
  const int w = tid >> 6;
  const int wm = w >> 1, wn = w & 1;             // wm: 32-row band, wn: 64-col band
  const long m0 = (long)blockIdx.x * 64;
  const long n0 = (long)blockIdx.y * 128;

  const int sr = lane >> 2;
  const int sc = (lane & 3) * 8;
  const unsigned short* gA  = A + (m0 + w * 16 + sr) * (long)lda + sc;          // tile w
  const unsigned short* gB0 = B + (n0 + (w * 2 + 0) * 16 + sr) * (long)ldb + sc;
  const unsigned short* gB1 = B + (n0 + (w * 2 + 1) * 16 + sr) * (long)ldb + sc;

  f32x4 acc[2][4] = {};
  const int q8 = (lane >> 4) * 8;
  const int r16 = lane & 15;

  for (int k0 = 0; k0 < K; k0 += 64) {
#pragma unroll
    for (int h = 0; h < 2; ++h) {
      const int ko = k0 + h * 32;
      async_load16(gA + ko, Asm[h] + w * 512);
      async_load16(gB0 + ko, Bsm[h] + (w * 2 + 0) * 512);
      async_load16(gB1 + ko, Bsm[h] + (w * 2 + 1) * 512);
    }
    __syncthreads();
#pragma unroll
    for (int h = 0; h < 2; ++h) {
      bf16x8 af[2], bfr[4];
#pragma unroll
      for (int i = 0; i < 2; ++i)
        af[i] = *reinterpret_cast<const bf16x8*>(Asm[h] + (wm * 32 + i * 16 + r16) * 32 + q8);
#pragma unroll
      for (int j = 0; j < 4; ++j)
        bfr[j] = *reinterpret_cast<const bf16x8*>(Bsm[h] + (wn * 64 + j * 16 + r16) * 32 + q8);
#pragma unroll
      for (int i = 0; i < 2; ++i)
#pragma unroll
        for (int j = 0; j < 4; ++j)
          acc[i][j] = __builtin_amdgcn_mfma_f32_16x16x32_bf16(af[i], bfr[j], acc[i][j], 0, 0, 0);
    }
    __syncthreads();
  }
  const int q = lane >> 4, cn = lane & 15;
#pragma unroll
  for (int i = 0; i < 2; ++i)
#pragma unroll
    for (int j = 0; j < 4; ++j) {
      long crow = m0 + wm * 32 + i * 16 + q * 4;
      long ccol = n0 + wn * 64 + j * 16 + cn;
#pragma unroll
      for (int r = 0; r < 4; ++r)
        C[(crow + r) * (long)ldc + ccol] = f2bf(acc[i][j][r]);
    }
}

// ---------------------------------------------------------------------------
// Fused: depthwise causal conv (width 4) + SiLU (blocks 0..CONV_GRID-1, 8
// timesteps per block) and dt/decay precompute (next 1024 blocks).
// Conv: thread owns 8 consecutive channels + 1 tail channel.
// dtprep: one 32-lane group per (db,h,chunk); ddg[task][128] dt/cd/W/P.
// ---------------------------------------------------------------------------
#define CONV_GRID (2 * BSZ * (SEQ / 8))    // 1024

__global__ __launch_bounds__(256) void k_convdt(
    const __bf16* __restrict__ zxb,
    const float* __restrict__ cw_f, const float* __restrict__ cb_f,
    const float* __restrict__ cw_r, const float* __restrict__ cb_r,
    const float* __restrict__ dtb_f, const float* __restrict__ dtb_r,
    const float* __restrict__ al_f, const float* __restrict__ al_r,
    const int* __restrict__ lengths,
    __bf16* __restrict__ xb, float* __restrict__ ddg) {
  const int tid = threadIdx.x;

  if (blockIdx.x < CONV_GRID) {
    // ================= conv (8-timestep tile) =================
    const int bx = blockIdx.x;                // db*128 + tg
    const int tg = bx & 127;
    const int db = bx >> 7;
    const int b = db & 3;
    const int dir = db >> 2;
    const int len = lengths[b];
    const int t0 = tg * 8;

    const float* cw = dir ? cw_r : cw_f;
    const float* cb = dir ? cb_r : cb_f;

    const int cA = tid * 8;          // 8 consecutive channels in [0,2048)
    const int cB = 2048 + tid;       // tail channel in [2048,2304)

    float wA0[8], wA1[8], wA2[8], wA3[8], bA[8];
    float rA0[8], rA1[8], rA2[8], rA3[8];
#pragma unroll
    for (int j = 0; j < 8; ++j) {
      float4 w4 = *(const float4*)(cw + (size_t)(cA + j) * 4);
      wA0[j] = w4.x; wA1[j] = w4.y; wA2[j] = w4.z; wA3[j] = w4.w;
      bA[j] = cb[cA + j];
      rA0[j] = 0.f; rA1[j] = 0.f; rA2[j] = 0.f;
    }
    float4 wB4 = *(const float4*)(cw + (size_t)cB * 4);
    float bB = cb[cB];
    float rB0 = 0.f, rB1 = 0.f, rB2 = 0.f, rB3;

    auto rowptr = [&](int tt) -> const __bf16* {
      int s = dir ? ((tt < len) ? (len - 1 - tt) : tt) : tt;
      return zxb + ((size_t)b * SEQ + s) * DPROJ_PAD + DINNER;
    };
    auto loadA = [&](const __bf16* rp, float* dst) {
      bf16x8 v = *(const bf16x8*)(rp + cA);
#pragma unroll
      for (int j = 0; j < 8; ++j) dst[j] = (float)v[j];
    };

    if (t0 >= 3) {
      const __bf16* ra = rowptr(t0 - 3);
      const __bf16* rb = rowptr(t0 - 2);
      const __bf16* rc = rowptr(t0 - 1);
      loadA(ra, rA0); loadA(rb, rA1); loadA(rc, rA2);
      rB0 = (float)ra[cB]; rB1 = (float)rb[cB]; rB2 = (float)rc[cB];
    }
    {
      const __bf16* rp = rowptr(t0);
      loadA(rp, rA3);
      rB3 = (float)rp[cB];
    }
    for (int j = 0; j < 8; ++j) {
      float r4A[8] = {};
      float r4B = 0.f;
      if (j < 7) {
        const __bf16* rp = rowptr(t0 + j + 1);
        loadA(rp, r4A);
        r4B = (float)rp[cB];
      }
      __bf16* orow = xb + ((size_t)db * SEQ + t0 + j) * CONVDIM;
      bf16x8 ov;
#pragma unroll
      for (int k = 0; k < 8; ++k) {
        float acc = bA[k];
        acc = fmaf(wA0[k], rA0[k], acc);
        acc = fmaf(wA1[k], rA1[k], acc);
        acc = fmaf(wA2[k], rA2[k], acc);
        acc = fmaf(wA3[k], rA3[k], acc);
        float sig = 1.f / (1.f + __expf(-acc));
        ov[k] = (__bf16)(acc * sig);
        rA0[k] = rA1[k]; rA1[k] = rA2[k]; rA2[k] = rA3[k]; rA3[k] = r4A[k];
      }
      *(bf16x8*)(orow + cA) = ov;
      {
        float acc = bB;
        acc = fmaf(wB4.x, rB0, acc);
        acc = fmaf(wB4.y, rB1, acc);
        acc = fmaf(wB4.z, rB2, acc);
        acc = fmaf(wB4.w, rB3, acc);
        float sig = 1.f / (1.f + __expf(-acc));
        orow[cB] = (__bf16)(acc * sig);
        rB0 = rB1; rB1 = rB2; rB2 = rB3; rB3 = r4B;
      }
    }
  } else {
    // ================= dtprep =================
    const int task = ((blockIdx.x - CONV_GRID) * 256 + tid) >> 5;  // (db*32+h)*32+chunk
    const int l32 = tid & 31;
    const int chunk = task & 31, hh = (task >> 5) & 31, db = task >> 10;
    const int b = db & 3, dir = db >> 2;
    const int len = lengths[b];
    const float dtbv = (dir ? dtb_r : dtb_f)[hh];
    const float Ah = -__expf((dir ? al_r : al_f)[hh]);
    const int s = chunk * 32 + l32;
    const int sf = dir ? ((s < len) ? (len - 1 - s) : s) : s;
    float raw = (float)zxb[(size_t)(b * SEQ + sf) * DPROJ_PAD + DINNER + CONVDIM + hh] + dtbv;
    float d = (raw > 20.f) ? raw : log1pf(__expf(raw));
    float cum = d;
#pragma unroll
    for (int o = 1; o < 32; o <<= 1) {
      float v = __shfl_up(cum, o, 32);
      if (l32 >= o) cum += v;
    }
    float cum31 = __shfl(cum, 31, 32);
    float* o = ddg + (size_t)task * 128;
    o[l32]      = d;
    o[32 + l32] = Ah * cum;
    o[64 + l32] = d * __expf(Ah * (cum31 - cum));
    o[96 + l32] = __expf(Ah * cum);
  }
}

// ---------------------------------------------------------------------------
// Chunked MFMA selective scan, frag-linear LDS (R7 structure, frozen).
// Single-buffered raw staging, 2 blocks/CU.
// ---------------------------------------------------------------------------
__global__ __launch_bounds__(256, 2) void k_scan(
    const __bf16* __restrict__ xb, const float* __restrict__ ddg,
    const float* __restrict__ D_f, const float* __restrict__ D_r,
    unsigned short* __restrict__ y) {
  __shared__ __bf16 Crawf[4096];      // C frag-linear, 8 tiles (tt,kk)
  __shared__ __bf16 Brawf[4096];      // B frag-linear (B-as-rows x k=n)
  __shared__ __bf16 Braw2[4096];      // B row-major [s][n] (for BT repack)
  __shared__ __bf16 BTf[4096];        // B^T frag-linear, 8 tiles (ng)
  __shared__ float  ddL[2][128];      // dt/cd/W/P tables (double)
  __shared__ __bf16 SL[1024];         // S frag-linear, 2 tiles (t-halves)
  __shared__ __bf16 HL[4][2048];      // per-wave H frag-linear, 4 tiles (kk)
  __shared__ __bf16 yO[2][32 * 72];   // y chunk [t][p], stride 72 (double)

  const int bx = blockIdx.x;          // db*32 + h
  const int h = bx & 31;
  const int db = bx >> 5;
  const int dir = db >> 2;
  const int tid = threadIdx.x;
  const int lane = tid & 63;
  const int w = tid >> 6;
  const int l15 = lane & 15;
  const int q = lane >> 4;

  const float Dh = (dir ? D_r : D_f)[h];
  const __bf16* xbase = xb + (size_t)db * SEQ * CONVDIM;
  const float* ddbase = ddg + (size_t)bx * NCHK * 128;
  unsigned short* ybase = y + (size_t)db * SEQ * DINNER + h * HEADDIM;

  for (int i = lane; i < 2048; i += 64) HL[w][i] = (__bf16)0.f;
  for (int i = tid; i < 1024; i += 256) SL[i] = (__bf16)0.f;

  f32x4 accH[8] = {};

  auto issue = [&](int c, int nb) {
    const __bf16* xr = xbase + (size_t)c * CH * CONVDIM;
#pragma unroll
    for (int k = 0; k < 2; ++k) {
      const int idx = w * 2 + k;              // 0..7
      const int P = idx * 64 + lane;
      const int tt = P >> 8, kk = (P >> 6) & 3, qq = (P >> 4) & 3, ll = P & 15;
      const __bf16* gB = xr + (size_t)(tt * 16 + ll) * CONVDIM + DINNER + kk * 32 + qq * 8;
      async_load16(gB, &Brawf[idx * 512]);
      async_load16(gB + 128, &Crawf[idx * 512]);
      const int s = P >> 4, n8 = P & 15;
      const __bf16* g2 = xr + (size_t)s * CONVDIM + DINNER + n8 * 8;
      async_load16(g2, &Braw2[idx * 512]);
    }
    if (w == 3 && lane < 32)
      async_load16(ddbase + (size_t)c * 128 + lane * 4, &ddL[nb][0]);
  };

  auto load_xt = [&](int c) {
    bf16x8 v;
    const __bf16* gx = xbase + (size_t)(c * CH + q * 8) * CONVDIM + h * HEADDIM + w * 16 + l15;
#pragma unroll
    for (int j = 0; j < 8; ++j) v[j] = gx[(size_t)j * CONVDIM];
    return v;
  };

  issue(0, 0);
  bf16x8 xt = load_xt(0);
  __syncthreads();

  for (int c = 0; c < NCHK; ++c) {
    const int cb = c & 1, nb = cb ^ 1;

    // ---------------- phase 1 (reads of raw staging buffers) ----------------
    if (c > 0) {   // flush previous chunk's y (coalesced)
      const int tf = tid >> 3, p8 = (tid & 7) * 8;
      bf16x8 vy = *(const bf16x8*)&yO[nb][tf * 72 + p8];
      *(bf16x8*)(ybase + (size_t)((c - 1) * CH + tf) * DINNER + p8) = vy;
    }

    // B^T repack from row-major Braw2
    {
      const int n = tid & 127, sg = tid >> 7;
#pragma unroll
      for (int e = 0; e < 2; ++e) {
        const int qp = sg * 2 + e;            // q' = s>>3
        bf16x8 v;
#pragma unroll
        for (int j = 0; j < 8; ++j) v[j] = Braw2[(qp * 8 + j) * 128 + n];
        *(bf16x8*)&BTf[((n >> 4) * 64 + qp * 16 + (n & 15)) * 8] = v;
      }
    }

    // C frags (all waves); G quadrant + mask (waves 0-2)
    bf16x8 Cf0[4], Cf1[4];
#pragma unroll
    for (int kk = 0; kk < 4; ++kk) {
      Cf0[kk] = *(const bf16x8*)&Crawf[(kk * 64 + lane) * 8];
      Cf1[kk] = *(const bf16x8*)&Crawf[((4 + kk) * 64 + lane) * 8];
    }
    if (w < 3) {
      const int tt = (w == 0) ? 0 : 1;
      const int ss = (w == 2) ? 1 : 0;
      f32x4 G = {};
#pragma unroll
      for (int kk = 0; kk < 4; ++kk) {
        bf16x8 Bq = *(const bf16x8*)&Brawf[((ss * 4 + kk) * 64 + lane) * 8];
        G = __builtin_amdgcn_mfma_f32_16x16x32_bf16(tt ? Cf1[kk] : Cf0[kk], Bq, G, 0, 0, 0);
      }
      const int sgl = ss * 16 + l15;
      const float sdt = ddL[cb][sgl];
      const float scd = ddL[cb][32 + sgl];
#pragma unroll
      for (int r = 0; r < 4; ++r) {
        const int t0 = q * 4 + r;
        float v = G[r] * sdt * __expf(ddL[cb][32 + tt * 16 + t0] - scd);
        if (tt == ss) {
          if (t0 < l15) v = 0.f;
          else if (t0 == l15) v += Dh;         // absorb D*x into S diagonal
        }
        SL[(tt * 64 + (ss * 2 + (l15 >> 3)) * 16 + t0) * 8 + (l15 & 7)] = (__bf16)v;
      }
    }
    __syncthreads();   // barrier A — raw-buffer reads complete block-wide

    // ---------------- phase 2 ----------------
    if (c + 1 < NCHK) issue(c + 1, nb);       // safe: single-buffer overwrite
    bf16x8 xt_n;
    if (c + 1 < NCHK) xt_n = load_xt(c + 1);

    // y_intra: y^T[p][t] = X^T @ S^T
    f32x4 accy0 = {}, accy1 = {};
    {
      bf16x8 S0 = *(const bf16x8*)&SL[(lane) * 8];
      bf16x8 S1 = *(const bf16x8*)&SL[(64 + lane) * 8];
      accy0 = __builtin_amdgcn_mfma_f32_16x16x32_bf16(xt, S0, accy0, 0, 0, 0);
      accy1 = __builtin_amdgcn_mfma_f32_16x16x32_bf16(xt, S1, accy1, 0, 0, 0);
    }
    // y_inter: (H_prev @ C^T) .* P_t
    {
      f32x4 ai0 = {}, ai1 = {};
#pragma unroll
      for (int kk = 0; kk < 4; ++kk) {
        bf16x8 Hf = *(const bf16x8*)&HL[w][(kk * 64 + lane) * 8];
        ai0 = __builtin_amdgcn_mfma_f32_16x16x32_bf16(Hf, Cf0[kk], ai0, 0, 0, 0);
        ai1 = __builtin_amdgcn_mfma_f32_16x16x32_bf16(Hf, Cf1[kk], ai1, 0, 0, 0);
      }
      const float P0 = ddL[cb][96 + l15], P1 = ddL[cb][96 + 16 + l15];
      accy0 = accy0 + ai0 * P0;
      accy1 = accy1 + ai1 * P1;
    }
    // H update: H = atot*H + (X.*W)^T @ B
    {
      const float atot = ddL[cb][96 + 31];
      bf16x8 xw;
#pragma unroll
      for (int j = 0; j < 8; ++j)
        xw[j] = (__bf16)((float)xt[j] * ddL[cb][64 + q * 8 + j]);
#pragma unroll
      for (int nt = 0; nt < 8; ++nt) {
        bf16x8 Bt = *(const bf16x8*)&BTf[(nt * 64 + lane) * 8];
        accH[nt] = accH[nt] * atot;
        accH[nt] = __builtin_amdgcn_mfma_f32_16x16x32_bf16(xw, Bt, accH[nt], 0, 0, 0);
      }
#pragma unroll
      for (int nt = 0; nt < 8; ++nt)
#pragma unroll
        for (int r = 0; r < 4; ++r) {
          const int n = nt * 16 + l15;
          HL[w][((n >> 5) * 64 + ((n & 31) >> 3) * 16 + q * 4 + r) * 8 + (n & 7)] =
              (__bf16)accH[nt][r];
        }
    }
    // stage y chunk
#pragma unroll
    for (int r = 0; r < 4; ++r) {
      const int p = w * 16 + q * 4 + r;
      yO[cb][l15 * 72 + p]        = (__bf16)accy0[r];
      yO[cb][(16 + l15) * 72 + p] = (__bf16)accy1[r];
    }
    xt = xt_n;
    __syncthreads();   // barrier B (drains async staging for c+1)
  }
  {  // final flush
    const int tf = tid >> 3, p8 = (tid & 7) * 8;
    bf16x8 vy = *(const bf16x8*)&yO[(NCHK - 1) & 1][tf * 72 + p8];
    *(bf16x8*)(ybase + (size_t)((NCHK - 1) * CH + tf) * DINNER + p8) = vy;
  }
}

// ---------------------------------------------------------------------------
// Gate (y * silu(z)) + RMSNorm per direction + average-with-flip -> bf16.
// ---------------------------------------------------------------------------
__global__ __launch_bounds__(256) void k_gate_combine(
    const __bf16* __restrict__ zxb, const unsigned short* __restrict__ y,
    const float* __restrict__ nw_f, const float* __restrict__ nw_r,
    const int* __restrict__ lengths, unsigned short* __restrict__ comb) {
  const int bx = blockIdx.x;            // b*SEQ + l
  const int b = bx >> 10, l = bx & 1023;
  const int tid = threadIdx.x;
  const int len = lengths[b];
  const int pos = (l < len) ? (len - 1 - l) : l;
  const int c0 = tid * 8;
  const __bf16* z = zxb + (size_t)bx * DPROJ_PAD;
  const __bf16* yf = (const __bf16*)(y + ((size_t)b * SEQ + l) * DINNER);
  const __bf16* yr = (const __bf16*)(y + ((size_t)(BSZ + b) * SEQ + pos) * DINNER);

  bf16x8 zv = *(const bf16x8*)(z + c0);
  bf16x8 yfv = *(const bf16x8*)(yf + c0);
  bf16x8 yrv = *(const bf16x8*)(yr + c0);
  float4 n0 = *(const float4*)(nw_f + c0);
  float4 n1 = *(const float4*)(nw_f + c0 + 4);
  float4 m0 = *(const float4*)(nw_r + c0);
  float4 m1 = *(const float4*)(nw_r + c0 + 4);

  float gf[8], gr[8];
  float sf = 0.f, sr = 0.f;
#pragma unroll
  for (int k = 0; k < 8; ++k) {
    float zz = (float)zv[k];
    float sz = zz / (1.f + __expf(-zz));
    float vf = (float)yfv[k] * sz;
    float vr = (float)yrv[k] * sz;
    gf[k] = vf; gr[k] = vr;
    sf += vf * vf; sr += vr * vr;
  }
  for (int o = 32; o > 0; o >>= 1) { sf += __shfl_down(sf, o); sr += __shfl_down(sr, o); }
  __shared__ float red[8];
  if ((tid & 63) == 0) { red[tid >> 6] = sf; red[4 + (tid >> 6)] = sr; }
  __syncthreads();
  sf = red[0] + red[1] + red[2] + red[3];
  sr = red[4] + red[5] + red[6] + red[7];
  float rf = rsqrtf(sf * (1.f / DINNER) + EPSF);
  float rr = rsqrtf(sr * (1.f / DINNER) + EPSF);
  const float nwf[8] = {n0.x, n0.y, n0.z, n0.w, n1.x, n1.y, n1.z, n1.w};
  const float nwr[8] = {m0.x, m0.y, m0.z, m0.w, m1.x, m1.y, m1.z, m1.w};
  bf16x8 ov;
#pragma unroll
  for (int k = 0; k < 8; ++k) {
    float o = 0.5f * (gf[k] * rf * nwf[k] + gr[k] * rr * nwr[k]);
    ov[k] = (__bf16)o;
  }
  *(bf16x8*)((__bf16*)comb + (size_t)bx * DINNER + c0) = ov;
}

// ---------------------------------------------------------------------------
extern "C" void kernel_launch(void* const* d_in, const int* in_sizes, int n_in,
                              void* d_out, int out_size, void* d_ws, size_t ws_size,
                              hipStream_t stream) {
  const float* hidden      = (const float*)d_in[0];
  const unsigned char* msk = (const unsigned char*)d_in[1];
  const float* in_proj_w   = (const float*)d_in[2];
  const float* out_proj_w  = (const float*)d_in[3];
  const float* conv_w_f    = (const float*)d_in[4];
  const float* conv_b_f    = (const float*)d_in[5];
  const float* dt_bias_f   = (const float*)d_in[6];
  const float* A_log_f     = (const float*)d_in[7];
  const float* D_f         = (const float*)d_in[8];
  const float* norm_w_f    = (const float*)d_in[9];
  const float* conv_w_r    = (const float*)d_in[10];
  const float* conv_b_r    = (const float*)d_in[11];
  const float* dt_bias_r   = (const float*)d_in[12];
  const float* A_log_r     = (const float*)d_in[13];
  const float* D_r         = (const float*)d_in[14];
  const float* norm_w_r    = (const float*)d_in[15];
  float* outF = (float*)d_out;

  char* ws = (char*)d_ws;
  size_t o_w1b  = 0;                         // bf16 [4480][1024]
  size_t o_w2b  = o_w1b  + 9175040;          // bf16 [1024][2048]
  size_t o_hb   = o_w2b  + 4194304;          // bf16 [4096][1024]
  size_t o_zx   = o_hb   + 8388608;          // bf16 [4096][4480]
  size_t o_xb   = o_zx   + 36700160;         // bf16 [2][4096][2304]
  size_t o_dd   = o_xb   + 37748736;         // f32  [8192][128]
  size_t o_y    = o_dd   + 4194304;          // bf16 [2][4096][2048]
  size_t o_comb = o_y    + 33554432;         // bf16 [4096][2048]
  size_t o_outp = o_comb + 16777216;         // bf16 [4096][1024]
  size_t o_len  = o_outp + 8388608;          // int  [4]

  unsigned short* W1b  = (unsigned short*)(ws + o_w1b);
  unsigned short* W2b  = (unsigned short*)(ws + o_w2b);
  unsigned short* hb   = (unsigned short*)(ws + o_hb);
  __bf16*         zxb  = (__bf16*)(ws + o_zx);
  __bf16*         xb   = (__bf16*)(ws + o_xb);
  float*          ddg  = (float*)(ws + o_dd);
  unsigned short* yB   = (unsigned short*)(ws + o_y);
  unsigned short* comb = (unsigned short*)(ws + o_comb);
  unsigned short* outp = (unsigned short*)(ws + o_outp);
  int*            lens = (int*)(ws + o_len);

  k_prep<<<CONV_BLKS + NTOK + BSZ, 256, 0, stream>>>(
      hidden, msk, in_proj_w, out_proj_w, W1b, W2b, hb, lens);

  k_gemm_bt_h64<<<dim3(NTOK / 64, DPROJ_PAD / 128), 256, 0, stream>>>(
      hb, W1b, (unsigned short*)zxb, DMODEL, DMODEL, DMODEL, DPROJ_PAD);

  k_convdt<<<CONV_GRID + 1024, 256, 0, stream>>>(
      zxb, conv_w_f, conv_b_f, conv_w_r, conv_b_r,
      dt_bias_f, dt_bias_r, A_log_f, A_log_r, lens, xb, ddg);

  k_scan<<<2 * BSZ * NHEADS, 256, 0, stream>>>(xb, ddg, D_f, D_r, yB);

  k_gate_combine<<<NTOK, 256, 0, stream>>>(zxb, yB, norm_w_f, norm_w_r, lens, comb);

  k_gemm_bt_h64<<<dim3(NTOK / 64, DMODEL / 128), 256, 0, stream>>>(
      comb, W2b, outp, DINNER, DINNER, DINNER, DMODEL);

  k_ln_out<<<NTOK, 256, 0, stream>>>(outp, outF);

  (void)in_sizes; (void)n_in; (void)out_size; (void)ws_size;
}